// Round 1
// baseline (1527.510 us; speedup 1.0000x reference)
//
#include <hip/hip_runtime.h>

#define N_ENT  30000
#define N_CON  29309
#define DIM    128
#define NBASIS 8
#define NREL   12
#define BATCH  256
#define LCON   50
#define SSEED  32
#define EDB    300000
#define ECON   200000

// ---------------------------------------------------------------- init
__global__ void deg_init_kernel(float* deg) {
    int i = blockIdx.x * blockDim.x + threadIdx.x;
    if (i < N_CON) deg[i] = 1.0f;   // self-loop contributes 1 to every node
}

// ---------------------------------------------------------------- RGCN
// msg[e,:] = sum_b comp[type[e],b] * basis[b, src[e], :]; agg[dst] += msg; cnt[dst] += 1
__global__ void rgcn_edge_kernel(const int* __restrict__ eidx, const int* __restrict__ etype,
                                 const float* __restrict__ comp, const float* __restrict__ basis,
                                 float* __restrict__ agg, float* __restrict__ cnt) {
    long long gid = (long long)blockIdx.x * blockDim.x + threadIdx.x;
    if (gid >= (long long)EDB * 32) return;
    int e  = (int)(gid >> 5);
    int d4 = (int)(gid & 31);
    int src = eidx[e];
    int dst = eidx[EDB + e];
    int t   = etype[e];
    const float* c = comp + t * NBASIS;
    float4 acc = make_float4(0.f, 0.f, 0.f, 0.f);
#pragma unroll
    for (int b = 0; b < NBASIS; ++b) {
        const float4* bp = (const float4*)(basis + ((size_t)b * N_ENT + src) * DIM);
        float4 v = bp[d4];
        float cb = c[b];
        acc.x += cb * v.x; acc.y += cb * v.y; acc.z += cb * v.z; acc.w += cb * v.w;
    }
    float* out = agg + (size_t)dst * DIM + d4 * 4;
    atomicAdd(out + 0, acc.x); atomicAdd(out + 1, acc.y);
    atomicAdd(out + 2, acc.z); atomicAdd(out + 3, acc.w);
    if (d4 == 0) atomicAdd(cnt + dst, 1.0f);
}

__global__ void rgcn_fin_kernel(const float* __restrict__ agg, const float* __restrict__ cnt,
                                const float* __restrict__ root, const float* __restrict__ bias,
                                float* __restrict__ dbf) {
    int i = blockIdx.x * blockDim.x + threadIdx.x;
    if (i >= N_ENT * DIM) return;
    int n = i >> 7, d = i & 127;
    dbf[i] = agg[i] / fmaxf(cnt[n], 1.0f) + root[i] + bias[d];
}

// ---------------------------------------------------------------- GCN
// xw = concept_emb @ gcn_w  (block: 16 rows, k-chunked W in LDS)
__global__ __launch_bounds__(128) void gcn_xw_kernel(const float* __restrict__ emb,
                                                     const float* __restrict__ W,
                                                     float* __restrict__ xw) {
    __shared__ float se[16 * DIM];
    __shared__ float sW[32 * DIM];
    int t = threadIdx.x;
    int row0 = blockIdx.x * 16;
    int nrows = min(16, N_CON - row0);
    for (int i = t; i < nrows * DIM; i += 128) se[i] = emb[row0 * DIM + i];
    float acc[16];
#pragma unroll
    for (int r = 0; r < 16; ++r) acc[r] = 0.f;
    for (int kc = 0; kc < 4; ++kc) {
        __syncthreads();
        for (int i = t; i < 32 * DIM / 4; i += 128)
            ((float4*)sW)[i] = ((const float4*)(W + kc * 32 * DIM))[i];
        __syncthreads();
        for (int k = 0; k < 32; ++k) {
            float w = sW[k * DIM + t];
#pragma unroll
            for (int r = 0; r < 16; ++r) acc[r] += se[r * DIM + kc * 32 + k] * w;
        }
    }
    for (int r = 0; r < nrows; ++r) xw[(row0 + r) * DIM + t] = acc[r];
}

__global__ void deg_acc_kernel(const int* __restrict__ cidx, float* __restrict__ deg) {
    int e = blockIdx.x * blockDim.x + threadIdx.x;
    if (e < ECON) atomicAdd(deg + cidx[ECON + e], 1.0f);
}

__global__ void dinv_kernel(const float* __restrict__ deg, float* __restrict__ dinv) {
    int i = blockIdx.x * blockDim.x + threadIdx.x;
    if (i < N_CON) dinv[i] = rsqrtf(deg[i]);   // deg >= 1 always (self-loops)
}

__global__ void gcn_edge_kernel(const int* __restrict__ cidx, const float* __restrict__ dinv,
                                const float* __restrict__ xw, float* __restrict__ conf) {
    long long gid = (long long)blockIdx.x * blockDim.x + threadIdx.x;
    if (gid >= (long long)ECON * 32) return;
    int e  = (int)(gid >> 5);
    int d4 = (int)(gid & 31);
    int cs = cidx[e];
    int cd = cidx[ECON + e];
    float norm = dinv[cs] * dinv[cd];
    float4 v = ((const float4*)(xw + (size_t)cs * DIM))[d4];
    float* o = conf + (size_t)cd * DIM + d4 * 4;
    atomicAdd(o + 0, norm * v.x); atomicAdd(o + 1, norm * v.y);
    atomicAdd(o + 2, norm * v.z); atomicAdd(o + 3, norm * v.w);
}

__global__ void gcn_fin_kernel(const float* __restrict__ dinv, const float* __restrict__ xw,
                               const float* __restrict__ gcn_b, float* __restrict__ conf) {
    int i = blockIdx.x * blockDim.x + threadIdx.x;
    if (i >= N_CON * DIM) return;
    int c = i >> 7, d = i & 127;
    float dv = dinv[c];
    conf[i] += dv * dv * xw[i] + gcn_b[d];   // analytic self-loop + bias
}

// ---------------------------------------------------------------- masked attention
// mode 0: seed (valid = s < lens[b], empty set -> zeros + mask); mode 1: concept (valid = idx != 0)
__global__ __launch_bounds__(128) void attn_kernel(const float* __restrict__ feats,
                                                   const int* __restrict__ idx,
                                                   const int* __restrict__ lens,
                                                   const float* __restrict__ A,
                                                   const float* __restrict__ vvec,
                                                   float* __restrict__ out_user,
                                                   float* __restrict__ out_mask,
                                                   int S, int mode) {
    __shared__ float h[LCON * DIM];
    __shared__ float sc[LCON];
    int b = blockIdx.x, t = threadIdx.x;
    const int* row = idx + b * S;
    for (int i = t; i < S * DIM; i += 128) {
        int s = i >> 7;
        h[i] = feats[(size_t)row[s] * DIM + (i & 127)];
    }
    if (t < S) sc[t] = 0.f;
    __syncthreads();
    for (int sd = t; sd < S * DIM; sd += 128) {
        int s = sd >> 7, d = sd & 127;
        float acc = 0.f;
        for (int k = 0; k < DIM; ++k) acc += h[(s << 7) + k] * A[(k << 7) + d];
        atomicAdd(&sc[s], tanhf(acc) * vvec[d]);
    }
    __syncthreads();
    int len = (mode == 0) ? lens[b] : 0;
    if (t == 0) {
        float m = -1e30f;
        for (int s = 0; s < S; ++s) {
            bool valid = (mode == 0) ? (s < len) : (row[s] != 0);
            float e = valid ? sc[s] : -1e30f;
            sc[s] = e;
            m = fmaxf(m, e);
        }
        float sum = 0.f;
        for (int s = 0; s < S; ++s) { float p = __expf(sc[s] - m); sum += p; sc[s] = p; }
        float inv = 1.f / sum;
        for (int s = 0; s < S; ++s) sc[s] *= inv;
    }
    __syncthreads();
    float acc = 0.f;
    for (int s = 0; s < S; ++s) acc += sc[s] * h[(s << 7) + t];
    if (mode == 0 && len == 0) acc = 0.f;
    out_user[(size_t)b * DIM + t] = acc;
    if (mode == 0 && t == 0) out_mask[b] = (len > 0) ? 1.f : 0.f;
}

// ---------------------------------------------------------------- gated fusion + info projection
__global__ __launch_bounds__(128) void fusion_kernel(const float* __restrict__ con_user,
                                                     const float* __restrict__ db_user,
                                                     const float* __restrict__ Wu, const float* __restrict__ bu,
                                                     const float* __restrict__ gw, const float* __restrict__ gb,
                                                     const float* __restrict__ Wi, const float* __restrict__ bi,
                                                     float* __restrict__ uemb, float* __restrict__ cone) {
    __shared__ float cu[DIM], du[DIM], red[DIM];
    int b = blockIdx.x, t = threadIdx.x;
    cu[t] = con_user[b * DIM + t];
    du[t] = db_user[b * DIM + t];
    __syncthreads();
    float u = bu[t];
    const float* wr = Wu + t * 2 * DIM;
    for (int k = 0; k < DIM; ++k) u += cu[k] * wr[k];
    for (int k = 0; k < DIM; ++k) u += du[k] * wr[DIM + k];
    red[t] = u * gw[t];
    __syncthreads();
    for (int s2 = 64; s2 > 0; s2 >>= 1) {
        if (t < s2) red[t] += red[t + s2];
        __syncthreads();
    }
    float gate = 1.f / (1.f + __expf(-(red[0] + gb[0])));
    uemb[b * DIM + t] = gate * du[t] + (1.f - gate) * cu[t];
    float ce = bi[t];
    const float* wi = Wi + t * DIM;
    for (int k = 0; k < DIM; ++k) ce += cu[k] * wi[k];
    cone[b * DIM + t] = ce;
}

// ---------------------------------------------------------------- fused scoring GEMMs
// entity_scores[b,n] = <uemb[b], dbf[n]> + en_b[n]
// sumsq[b] += (<cone[b], dbf[n]> + info_b[n] - db_vec[b,n])^2
__global__ __launch_bounds__(256) void score_kernel(const float* __restrict__ dbf,
                                                    const float* __restrict__ uemb,
                                                    const float* __restrict__ cone,
                                                    const float* __restrict__ en_b,
                                                    const float* __restrict__ info_b,
                                                    const float* __restrict__ db_vec,
                                                    float* __restrict__ escore,
                                                    float* __restrict__ sumsq) {
    __shared__ float sf[64 * 33];
    __shared__ float su[32 * 33];
    __shared__ float sc[32 * 33];
    __shared__ float ssq[32];
    int n0 = blockIdx.x * 64;
    int b0 = blockIdx.y * 32;
    int t  = threadIdx.x;
    if (t < 32) ssq[t] = 0.f;
    int tn = t & 15, tb = t >> 4;
    float aE[2][4] = {{0,0,0,0},{0,0,0,0}};
    float aD[2][4] = {{0,0,0,0},{0,0,0,0}};
    for (int kc = 0; kc < 4; ++kc) {
        __syncthreads();
        for (int i = t; i < 64 * 8; i += 256) {        // feats chunk [64 x 32]
            int n = i >> 3, re = i & 7;
            float4 v = make_float4(0.f, 0.f, 0.f, 0.f);
            if (n0 + n < N_ENT)
                v = ((const float4*)(dbf + (size_t)(n0 + n) * DIM + kc * 32))[re];
            float* d = sf + n * 33 + re * 4;
            d[0] = v.x; d[1] = v.y; d[2] = v.z; d[3] = v.w;
        }
        for (int i = t; i < 32 * 8; i += 256) {        // uemb/cone chunks [32 x 32]
            int bz = i >> 3, re = i & 7;
            float4 v = ((const float4*)(uemb + (size_t)(b0 + bz) * DIM + kc * 32))[re];
            float* d = su + bz * 33 + re * 4;
            d[0] = v.x; d[1] = v.y; d[2] = v.z; d[3] = v.w;
            float4 w = ((const float4*)(cone + (size_t)(b0 + bz) * DIM + kc * 32))[re];
            float* d2 = sc + bz * 33 + re * 4;
            d2[0] = w.x; d2[1] = w.y; d2[2] = w.z; d2[3] = w.w;
        }
        __syncthreads();
        const float* pu0 = su + (tb * 2) * 33;
        const float* pu1 = pu0 + 33;
        const float* pc0 = sc + (tb * 2) * 33;
        const float* pc1 = pc0 + 33;
        const float* pf  = sf + (tn * 4) * 33;
#pragma unroll
        for (int k = 0; k < 32; ++k) {
            float u0 = pu0[k], u1 = pu1[k], c0 = pc0[k], c1 = pc1[k];
            float f0 = pf[k], f1 = pf[33 + k], f2 = pf[66 + k], f3 = pf[99 + k];
            aE[0][0] += u0 * f0; aE[0][1] += u0 * f1; aE[0][2] += u0 * f2; aE[0][3] += u0 * f3;
            aE[1][0] += u1 * f0; aE[1][1] += u1 * f1; aE[1][2] += u1 * f2; aE[1][3] += u1 * f3;
            aD[0][0] += c0 * f0; aD[0][1] += c0 * f1; aD[0][2] += c0 * f2; aD[0][3] += c0 * f3;
            aD[1][0] += c1 * f0; aD[1][1] += c1 * f1; aD[1][2] += c1 * f2; aD[1][3] += c1 * f3;
        }
    }
#pragma unroll
    for (int i = 0; i < 2; ++i) {
        int b = b0 + tb * 2 + i;
        float local = 0.f;
#pragma unroll
        for (int j = 0; j < 4; ++j) {
            int n = n0 + tn * 4 + j;
            if (n < N_ENT) {
                escore[(size_t)b * N_ENT + n] = aE[i][j] + en_b[n];
                float dsc = aD[i][j] + info_b[n] - db_vec[(size_t)b * N_ENT + n];
                local += dsc * dsc;
            }
        }
        atomicAdd(&ssq[tb * 2 + i], local);
    }
    __syncthreads();
    if (t < 32) atomicAdd(sumsq + b0 + t, ssq[t]);
}

// ---------------------------------------------------------------- CE over entity_scores rows
__global__ __launch_bounds__(256) void ce_kernel(const float* __restrict__ scores,
                                                 const int* __restrict__ labels,
                                                 const float* __restrict__ rec,
                                                 float* __restrict__ rloss) {
    __shared__ float red[256];
    int b = blockIdx.x, t = threadIdx.x;
    const float* row = scores + (size_t)b * N_ENT;
    float m = -1e30f;
    for (int i = t; i < N_ENT; i += 256) m = fmaxf(m, row[i]);
    red[t] = m;
    __syncthreads();
    for (int s2 = 128; s2 > 0; s2 >>= 1) {
        if (t < s2) red[t] = fmaxf(red[t], red[t + s2]);
        __syncthreads();
    }
    m = red[0];
    __syncthreads();
    float sum = 0.f;
    for (int i = t; i < N_ENT; i += 256) sum += __expf(row[i] - m);
    red[t] = sum;
    __syncthreads();
    for (int s2 = 128; s2 > 0; s2 >>= 1) {
        if (t < s2) red[t] += red[t + s2];
        __syncthreads();
    }
    if (t == 0) {
        float lse = m + logf(red[0]);
        float ce  = -(row[labels[b]] - lse);
        rloss[b]  = ce * rec[b];
    }
}

__global__ __launch_bounds__(256) void final_kernel(const float* __restrict__ rloss,
                                                    const float* __restrict__ sumsq,
                                                    const float* __restrict__ maskv,
                                                    float* __restrict__ out) {
    __shared__ float r1[256], r2[256];
    int t = threadIdx.x;
    r1[t] = rloss[t];
    r2[t] = sumsq[t] * maskv[t];
    __syncthreads();
    for (int s2 = 128; s2 > 0; s2 >>= 1) {
        if (t < s2) { r1[t] += r1[t + s2]; r2[t] += r2[t + s2]; }
        __syncthreads();
    }
    if (t == 0) {
        float rec_loss = r1[0];
        float info = r2[0] / (float)BATCH;
        out[0] = rec_loss + 0.025f * info;
        out[1 + (size_t)BATCH * N_ENT] = rec_loss;
    }
}

// ---------------------------------------------------------------- launch
extern "C" void kernel_launch(void* const* d_in, const int* in_sizes, int n_in,
                              void* d_out, int out_size, void* d_ws, size_t ws_size,
                              hipStream_t stream) {
    (void)in_sizes; (void)n_in; (void)out_size; (void)ws_size;
    const int*   concept_mask  = (const int*)d_in[0];
    const int*   seed_pad      = (const int*)d_in[1];
    const int*   seed_lens     = (const int*)d_in[2];
    const int*   db_eidx       = (const int*)d_in[3];
    const int*   db_etype      = (const int*)d_in[4];
    const int*   con_eidx      = (const int*)d_in[5];
    const float* db_vec        = (const float*)d_in[6];
    const int*   labels        = (const int*)d_in[7];
    const float* rec           = (const float*)d_in[8];
    const float* concept_emb   = (const float*)d_in[9];
    const float* basis         = (const float*)d_in[10];
    const float* comp          = (const float*)d_in[11];
    const float* rgcn_root     = (const float*)d_in[12];
    const float* rgcn_bias     = (const float*)d_in[13];
    const float* gcn_w         = (const float*)d_in[14];
    const float* gcn_b         = (const float*)d_in[15];
    const float* attn_a        = (const float*)d_in[16];
    const float* attn_b        = (const float*)d_in[17];
    const float* attn_a_db     = (const float*)d_in[18];
    const float* attn_b_db     = (const float*)d_in[19];
    const float* user_norm_w   = (const float*)d_in[20];
    const float* user_norm_b   = (const float*)d_in[21];
    const float* gate_norm_w   = (const float*)d_in[22];
    const float* gate_norm_b   = (const float*)d_in[23];
    const float* info_con_w    = (const float*)d_in[24];
    const float* info_con_b    = (const float*)d_in[25];
    const float* info_out_db_b = (const float*)d_in[26];
    const float* output_en_b   = (const float*)d_in[27];

    float* ws = (float*)d_ws;
    size_t off = 0;
    auto alloc = [&](size_t n) { float* p = ws + off; off += (n + 255) & ~(size_t)255; return p; };
    float* agg   = alloc((size_t)N_ENT * DIM);
    float* cnt   = alloc(N_ENT);
    float* dbf   = alloc((size_t)N_ENT * DIM);
    float* xw    = alloc((size_t)N_CON * DIM);
    float* deg   = alloc(N_CON);
    float* dinv  = alloc(N_CON);
    float* conf  = alloc((size_t)N_CON * DIM);
    float* dbu   = alloc(BATCH * DIM);
    float* conu  = alloc(BATCH * DIM);
    float* maskv = alloc(BATCH);
    float* uemb  = alloc(BATCH * DIM);
    float* cone  = alloc(BATCH * DIM);
    float* ssq   = alloc(BATCH);
    float* rls   = alloc(BATCH);

    float* out    = (float*)d_out;
    float* escore = out + 1;

    hipMemsetAsync(agg,  0, (size_t)N_ENT * DIM * sizeof(float), stream);
    hipMemsetAsync(cnt,  0, N_ENT * sizeof(float), stream);
    hipMemsetAsync(conf, 0, (size_t)N_CON * DIM * sizeof(float), stream);
    hipMemsetAsync(ssq,  0, BATCH * sizeof(float), stream);

    deg_init_kernel<<<(N_CON + 255) / 256, 256, 0, stream>>>(deg);
    rgcn_edge_kernel<<<(EDB * 32) / 256, 256, 0, stream>>>(db_eidx, db_etype, comp, basis, agg, cnt);
    rgcn_fin_kernel<<<(N_ENT * DIM + 255) / 256, 256, 0, stream>>>(agg, cnt, rgcn_root, rgcn_bias, dbf);
    gcn_xw_kernel<<<(N_CON + 15) / 16, 128, 0, stream>>>(concept_emb, gcn_w, xw);
    deg_acc_kernel<<<(ECON + 255) / 256, 256, 0, stream>>>(con_eidx, deg);
    dinv_kernel<<<(N_CON + 255) / 256, 256, 0, stream>>>(deg, dinv);
    gcn_edge_kernel<<<(ECON * 32) / 256, 256, 0, stream>>>(con_eidx, dinv, xw, conf);
    gcn_fin_kernel<<<(N_CON * DIM + 255) / 256, 256, 0, stream>>>(dinv, xw, gcn_b, conf);
    attn_kernel<<<BATCH, 128, 0, stream>>>(dbf, seed_pad, seed_lens, attn_a_db, attn_b_db,
                                           dbu, maskv, SSEED, 0);
    attn_kernel<<<BATCH, 128, 0, stream>>>(conf, concept_mask, nullptr, attn_a, attn_b,
                                           conu, nullptr, LCON, 1);
    fusion_kernel<<<BATCH, 128, 0, stream>>>(conu, dbu, user_norm_w, user_norm_b,
                                             gate_norm_w, gate_norm_b, info_con_w, info_con_b,
                                             uemb, cone);
    dim3 sg((N_ENT + 63) / 64, BATCH / 32);
    score_kernel<<<sg, 256, 0, stream>>>(dbf, uemb, cone, output_en_b, info_out_db_b, db_vec,
                                         escore, ssq);
    ce_kernel<<<BATCH, 256, 0, stream>>>(escore, labels, rec, rls);
    final_kernel<<<1, 256, 0, stream>>>(rls, ssq, maskv, out);
}

// Round 2
// 912.192 us; speedup vs baseline: 1.6745x; 1.6745x over previous
//
#include <hip/hip_runtime.h>

#define N_ENT  30000
#define N_CON  29309
#define DIM    128
#define NBASIS 8
#define NREL   12
#define BATCH  256
#define LCON   50
#define SSEED  32
#define EDB    300000
#define ECON   200000

// ---------------------------------------------------------------- CSR build
__global__ void hist_kernel(const int* __restrict__ dsts, int n, int* __restrict__ cnt) {
    int e = blockIdx.x * blockDim.x + threadIdx.x;
    if (e < n) atomicAdd(cnt + dsts[e], 1);
}

// single-block exclusive scan of cnt[0..n) -> rowptr[0..n], cursor copy
__global__ __launch_bounds__(1024) void scan_kernel(const int* __restrict__ cnt, int n,
                                                    int* __restrict__ rowptr,
                                                    int* __restrict__ cursor) {
    __shared__ int part[1024];
    int t = threadIdx.x;
    int per = (n + 1023) / 1024;
    int s0 = t * per;
    int sum = 0;
    for (int i = 0; i < per; ++i) {
        int idx = s0 + i;
        if (idx < n) sum += cnt[idx];
    }
    part[t] = sum;
    __syncthreads();
    for (int off = 1; off < 1024; off <<= 1) {
        int v = (t >= off) ? part[t - off] : 0;
        __syncthreads();
        part[t] += v;
        __syncthreads();
    }
    int run = part[t] - sum;   // exclusive prefix for this thread's chunk
    for (int i = 0; i < per; ++i) {
        int idx = s0 + i;
        if (idx < n) {
            rowptr[idx] = run;
            cursor[idx] = run;
            run += cnt[idx];
        }
    }
    if (t == 1023) rowptr[n] = part[1023];
}

// pack src | type<<18 (src < 2^18, type < 12)
__global__ void scatter_rgcn_kernel(const int* __restrict__ eidx, const int* __restrict__ etype,
                                    int* __restrict__ cursor, int* __restrict__ elist) {
    int e = blockIdx.x * blockDim.x + threadIdx.x;
    if (e >= EDB) return;
    int dst = eidx[EDB + e];
    int pos = atomicAdd(cursor + dst, 1);
    elist[pos] = eidx[e] | (etype[e] << 18);
}

__global__ void scatter_gcn_kernel(const int* __restrict__ cidx,
                                   int* __restrict__ cursor, int* __restrict__ elist) {
    int e = blockIdx.x * blockDim.x + threadIdx.x;
    if (e >= ECON) return;
    int dst = cidx[ECON + e];
    int pos = atomicAdd(cursor + dst, 1);
    elist[pos] = cidx[e];
}

// ---------------------------------------------------------------- RGCN
// w[r,n,:] = sum_b comp[r,b] * basis[b,n,:]
__global__ __launch_bounds__(256) void wcomp_kernel(const float* __restrict__ basis,
                                                    const float* __restrict__ comp,
                                                    float* __restrict__ w) {
    __shared__ float sc[NREL * NBASIS];
    int t = threadIdx.x;
    if (t < NREL * NBASIS) sc[t] = comp[t];
    __syncthreads();
    int i = blockIdx.x * blockDim.x + t;
    if (i >= N_ENT * 32) return;
    int n = i >> 5, d4 = i & 31;
    float4 bv[NBASIS];
#pragma unroll
    for (int b = 0; b < NBASIS; ++b)
        bv[b] = ((const float4*)(basis + ((size_t)b * N_ENT + n) * DIM))[d4];
#pragma unroll
    for (int r = 0; r < NREL; ++r) {
        float4 acc = make_float4(0.f, 0.f, 0.f, 0.f);
#pragma unroll
        for (int b = 0; b < NBASIS; ++b) {
            float c = sc[r * NBASIS + b];
            acc.x += c * bv[b].x; acc.y += c * bv[b].y;
            acc.z += c * bv[b].z; acc.w += c * bv[b].w;
        }
        ((float4*)(w + ((size_t)r * N_ENT + n) * DIM))[d4] = acc;
    }
}

// one wave per dst entity; fused mean + root + bias
__global__ __launch_bounds__(256) void rgcn_gather_w(const int* __restrict__ rowptr,
                                                     const int* __restrict__ elist,
                                                     const float* __restrict__ w,
                                                     const float* __restrict__ root,
                                                     const float* __restrict__ bias,
                                                     float* __restrict__ dbf) {
    int wid  = blockIdx.x * 4 + (threadIdx.x >> 6);
    int lane = threadIdx.x & 63;
    if (wid >= N_ENT) return;
    int beg = rowptr[wid], end = rowptr[wid + 1];
    float a0 = 0.f, a1 = 0.f;
    int p = beg;
    for (; p + 1 < end; p += 2) {
        int v0 = elist[p], v1 = elist[p + 1];
        const float* w0 = w + ((size_t)(v0 >> 18) * N_ENT + (v0 & 0x3FFFF)) * DIM;
        const float* w1 = w + ((size_t)(v1 >> 18) * N_ENT + (v1 & 0x3FFFF)) * DIM;
        a0 += w0[lane] + w1[lane];
        a1 += w0[lane + 64] + w1[lane + 64];
    }
    if (p < end) {
        int v = elist[p];
        const float* wr = w + ((size_t)(v >> 18) * N_ENT + (v & 0x3FFFF)) * DIM;
        a0 += wr[lane]; a1 += wr[lane + 64];
    }
    float inv = 1.f / fmaxf((float)(end - beg), 1.f);
    size_t base = (size_t)wid * DIM;
    dbf[base + lane]      = a0 * inv + root[base + lane]      + bias[lane];
    dbf[base + lane + 64] = a1 * inv + root[base + lane + 64] + bias[lane + 64];
}

// fallback when ws too small for w: gather straight from basis
__global__ __launch_bounds__(256) void rgcn_gather_basis(const int* __restrict__ rowptr,
                                                         const int* __restrict__ elist,
                                                         const float* __restrict__ basis,
                                                         const float* __restrict__ comp,
                                                         const float* __restrict__ root,
                                                         const float* __restrict__ bias,
                                                         float* __restrict__ dbf) {
    int wid  = blockIdx.x * 4 + (threadIdx.x >> 6);
    int lane = threadIdx.x & 63;
    if (wid >= N_ENT) return;
    int beg = rowptr[wid], end = rowptr[wid + 1];
    float a0 = 0.f, a1 = 0.f;
    for (int p = beg; p < end; ++p) {
        int v = elist[p];
        int src = v & 0x3FFFF, ty = v >> 18;
        const float* c = comp + ty * NBASIS;
#pragma unroll
        for (int b = 0; b < NBASIS; ++b) {
            const float* bp = basis + ((size_t)b * N_ENT + src) * DIM;
            a0 += c[b] * bp[lane];
            a1 += c[b] * bp[lane + 64];
        }
    }
    float inv = 1.f / fmaxf((float)(end - beg), 1.f);
    size_t base = (size_t)wid * DIM;
    dbf[base + lane]      = a0 * inv + root[base + lane]      + bias[lane];
    dbf[base + lane + 64] = a1 * inv + root[base + lane + 64] + bias[lane + 64];
}

// ---------------------------------------------------------------- GCN
__global__ __launch_bounds__(128) void gcn_xw_kernel(const float* __restrict__ emb,
                                                     const float* __restrict__ W,
                                                     float* __restrict__ xw) {
    __shared__ float se[16 * DIM];
    __shared__ float sW[32 * DIM];
    int t = threadIdx.x;
    int row0 = blockIdx.x * 16;
    int nrows = min(16, N_CON - row0);
    for (int i = t; i < nrows * DIM; i += 128) se[i] = emb[row0 * DIM + i];
    float acc[16];
#pragma unroll
    for (int r = 0; r < 16; ++r) acc[r] = 0.f;
    for (int kc = 0; kc < 4; ++kc) {
        __syncthreads();
        for (int i = t; i < 32 * DIM / 4; i += 128)
            ((float4*)sW)[i] = ((const float4*)(W + kc * 32 * DIM))[i];
        __syncthreads();
        for (int k = 0; k < 32; ++k) {
            float w = sW[k * DIM + t];
#pragma unroll
            for (int r = 0; r < 16; ++r) acc[r] += se[r * DIM + kc * 32 + k] * w;
        }
    }
    for (int r = 0; r < nrows; ++r) xw[(row0 + r) * DIM + t] = acc[r];
}

__global__ void dinv_kernel(const int* __restrict__ cnt, float* __restrict__ dinv) {
    int i = blockIdx.x * blockDim.x + threadIdx.x;
    if (i < N_CON) dinv[i] = rsqrtf((float)(cnt[i] + 1));   // +1 self-loop, deg>=1
}

// one wave per concept node; conf = dv*(sum dinv[src]*xw[src]) + dv^2*xw[self] + bias
__global__ __launch_bounds__(256) void gcn_gather(const int* __restrict__ rowptr,
                                                  const int* __restrict__ elist,
                                                  const float* __restrict__ dinv,
                                                  const float* __restrict__ xw,
                                                  const float* __restrict__ gcn_b,
                                                  float* __restrict__ conf) {
    int wid  = blockIdx.x * 4 + (threadIdx.x >> 6);
    int lane = threadIdx.x & 63;
    if (wid >= N_CON) return;
    int beg = rowptr[wid], end = rowptr[wid + 1];
    float a0 = 0.f, a1 = 0.f;
    int p = beg;
    for (; p + 1 < end; p += 2) {
        int s0 = elist[p], s1 = elist[p + 1];
        float n0 = dinv[s0], n1 = dinv[s1];
        const float* x0 = xw + (size_t)s0 * DIM;
        const float* x1 = xw + (size_t)s1 * DIM;
        a0 += n0 * x0[lane]      + n1 * x1[lane];
        a1 += n0 * x0[lane + 64] + n1 * x1[lane + 64];
    }
    if (p < end) {
        int s = elist[p];
        float nm = dinv[s];
        const float* x = xw + (size_t)s * DIM;
        a0 += nm * x[lane]; a1 += nm * x[lane + 64];
    }
    float dv = dinv[wid];
    size_t base = (size_t)wid * DIM;
    conf[base + lane]      = dv * a0 + dv * dv * xw[base + lane]      + gcn_b[lane];
    conf[base + lane + 64] = dv * a1 + dv * dv * xw[base + lane + 64] + gcn_b[lane + 64];
}

// ---------------------------------------------------------------- masked attention
__global__ __launch_bounds__(128) void attn_kernel(const float* __restrict__ feats,
                                                   const int* __restrict__ idx,
                                                   const int* __restrict__ lens,
                                                   const float* __restrict__ A,
                                                   const float* __restrict__ vvec,
                                                   float* __restrict__ out_user,
                                                   float* __restrict__ out_mask,
                                                   int S, int mode) {
    __shared__ float h[LCON * DIM];
    __shared__ float sc[LCON];
    int b = blockIdx.x, t = threadIdx.x;
    const int* row = idx + b * S;
    for (int i = t; i < S * DIM; i += 128) {
        int s = i >> 7;
        h[i] = feats[(size_t)row[s] * DIM + (i & 127)];
    }
    if (t < S) sc[t] = 0.f;
    __syncthreads();
    for (int sd = t; sd < S * DIM; sd += 128) {
        int s = sd >> 7, d = sd & 127;
        float acc = 0.f;
        for (int k = 0; k < DIM; ++k) acc += h[(s << 7) + k] * A[(k << 7) + d];
        atomicAdd(&sc[s], tanhf(acc) * vvec[d]);
    }
    __syncthreads();
    int len = (mode == 0) ? lens[b] : 0;
    if (t == 0) {
        float m = -1e30f;
        for (int s = 0; s < S; ++s) {
            bool valid = (mode == 0) ? (s < len) : (row[s] != 0);
            float e = valid ? sc[s] : -1e30f;
            sc[s] = e;
            m = fmaxf(m, e);
        }
        float sum = 0.f;
        for (int s = 0; s < S; ++s) { float p = __expf(sc[s] - m); sum += p; sc[s] = p; }
        float inv = 1.f / sum;
        for (int s = 0; s < S; ++s) sc[s] *= inv;
    }
    __syncthreads();
    float acc = 0.f;
    for (int s = 0; s < S; ++s) acc += sc[s] * h[(s << 7) + t];
    if (mode == 0 && len == 0) acc = 0.f;
    out_user[(size_t)b * DIM + t] = acc;
    if (mode == 0 && t == 0) out_mask[b] = (len > 0) ? 1.f : 0.f;
}

// ---------------------------------------------------------------- gated fusion + info projection
__global__ __launch_bounds__(128) void fusion_kernel(const float* __restrict__ con_user,
                                                     const float* __restrict__ db_user,
                                                     const float* __restrict__ Wu, const float* __restrict__ bu,
                                                     const float* __restrict__ gw, const float* __restrict__ gb,
                                                     const float* __restrict__ Wi, const float* __restrict__ bi,
                                                     float* __restrict__ uemb, float* __restrict__ cone) {
    __shared__ float cu[DIM], du[DIM], red[DIM];
    int b = blockIdx.x, t = threadIdx.x;
    cu[t] = con_user[b * DIM + t];
    du[t] = db_user[b * DIM + t];
    __syncthreads();
    float u = bu[t];
    const float* wr = Wu + t * 2 * DIM;
    for (int k = 0; k < DIM; ++k) u += cu[k] * wr[k];
    for (int k = 0; k < DIM; ++k) u += du[k] * wr[DIM + k];
    red[t] = u * gw[t];
    __syncthreads();
    for (int s2 = 64; s2 > 0; s2 >>= 1) {
        if (t < s2) red[t] += red[t + s2];
        __syncthreads();
    }
    float gate = 1.f / (1.f + __expf(-(red[0] + gb[0])));
    uemb[b * DIM + t] = gate * du[t] + (1.f - gate) * cu[t];
    float ce = bi[t];
    const float* wi = Wi + t * DIM;
    for (int k = 0; k < DIM; ++k) ce += cu[k] * wi[k];
    cone[b * DIM + t] = ce;
}

// ---------------------------------------------------------------- fused scoring GEMMs
__global__ __launch_bounds__(256) void score_kernel(const float* __restrict__ dbf,
                                                    const float* __restrict__ uemb,
                                                    const float* __restrict__ cone,
                                                    const float* __restrict__ en_b,
                                                    const float* __restrict__ info_b,
                                                    const float* __restrict__ db_vec,
                                                    float* __restrict__ escore,
                                                    float* __restrict__ sumsq) {
    __shared__ float sf[64 * 33];
    __shared__ float su[32 * 33];
    __shared__ float sc[32 * 33];
    __shared__ float ssq[32];
    int n0 = blockIdx.x * 64;
    int b0 = blockIdx.y * 32;
    int t  = threadIdx.x;
    if (t < 32) ssq[t] = 0.f;
    int tn = t & 15, tb = t >> 4;
    float aE[2][4] = {{0,0,0,0},{0,0,0,0}};
    float aD[2][4] = {{0,0,0,0},{0,0,0,0}};
    for (int kc = 0; kc < 4; ++kc) {
        __syncthreads();
        for (int i = t; i < 64 * 8; i += 256) {
            int n = i >> 3, re = i & 7;
            float4 v = make_float4(0.f, 0.f, 0.f, 0.f);
            if (n0 + n < N_ENT)
                v = ((const float4*)(dbf + (size_t)(n0 + n) * DIM + kc * 32))[re];
            float* d = sf + n * 33 + re * 4;
            d[0] = v.x; d[1] = v.y; d[2] = v.z; d[3] = v.w;
        }
        for (int i = t; i < 32 * 8; i += 256) {
            int bz = i >> 3, re = i & 7;
            float4 v = ((const float4*)(uemb + (size_t)(b0 + bz) * DIM + kc * 32))[re];
            float* d = su + bz * 33 + re * 4;
            d[0] = v.x; d[1] = v.y; d[2] = v.z; d[3] = v.w;
            float4 w = ((const float4*)(cone + (size_t)(b0 + bz) * DIM + kc * 32))[re];
            float* d2 = sc + bz * 33 + re * 4;
            d2[0] = w.x; d2[1] = w.y; d2[2] = w.z; d2[3] = w.w;
        }
        __syncthreads();
        const float* pu0 = su + (tb * 2) * 33;
        const float* pu1 = pu0 + 33;
        const float* pc0 = sc + (tb * 2) * 33;
        const float* pc1 = pc0 + 33;
        const float* pf  = sf + (tn * 4) * 33;
#pragma unroll
        for (int k = 0; k < 32; ++k) {
            float u0 = pu0[k], u1 = pu1[k], c0 = pc0[k], c1 = pc1[k];
            float f0 = pf[k], f1 = pf[33 + k], f2 = pf[66 + k], f3 = pf[99 + k];
            aE[0][0] += u0 * f0; aE[0][1] += u0 * f1; aE[0][2] += u0 * f2; aE[0][3] += u0 * f3;
            aE[1][0] += u1 * f0; aE[1][1] += u1 * f1; aE[1][2] += u1 * f2; aE[1][3] += u1 * f3;
            aD[0][0] += c0 * f0; aD[0][1] += c0 * f1; aD[0][2] += c0 * f2; aD[0][3] += c0 * f3;
            aD[1][0] += c1 * f0; aD[1][1] += c1 * f1; aD[1][2] += c1 * f2; aD[1][3] += c1 * f3;
        }
    }
#pragma unroll
    for (int i = 0; i < 2; ++i) {
        int b = b0 + tb * 2 + i;
        float local = 0.f;
#pragma unroll
        for (int j = 0; j < 4; ++j) {
            int n = n0 + tn * 4 + j;
            if (n < N_ENT) {
                escore[(size_t)b * N_ENT + n] = aE[i][j] + en_b[n];
                float dsc = aD[i][j] + info_b[n] - db_vec[(size_t)b * N_ENT + n];
                local += dsc * dsc;
            }
        }
        atomicAdd(&ssq[tb * 2 + i], local);
    }
    __syncthreads();
    if (t < 32) atomicAdd(sumsq + b0 + t, ssq[t]);
}

// ---------------------------------------------------------------- CE
__global__ __launch_bounds__(256) void ce_kernel(const float* __restrict__ scores,
                                                 const int* __restrict__ labels,
                                                 const float* __restrict__ rec,
                                                 float* __restrict__ rloss) {
    __shared__ float red[256];
    int b = blockIdx.x, t = threadIdx.x;
    const float* row = scores + (size_t)b * N_ENT;
    float m = -1e30f;
    for (int i = t; i < N_ENT; i += 256) m = fmaxf(m, row[i]);
    red[t] = m;
    __syncthreads();
    for (int s2 = 128; s2 > 0; s2 >>= 1) {
        if (t < s2) red[t] = fmaxf(red[t], red[t + s2]);
        __syncthreads();
    }
    m = red[0];
    __syncthreads();
    float sum = 0.f;
    for (int i = t; i < N_ENT; i += 256) sum += __expf(row[i] - m);
    red[t] = sum;
    __syncthreads();
    for (int s2 = 128; s2 > 0; s2 >>= 1) {
        if (t < s2) red[t] += red[t + s2];
        __syncthreads();
    }
    if (t == 0) {
        float lse = m + logf(red[0]);
        float ce  = -(row[labels[b]] - lse);
        rloss[b]  = ce * rec[b];
    }
}

__global__ __launch_bounds__(256) void final_kernel(const float* __restrict__ rloss,
                                                    const float* __restrict__ sumsq,
                                                    const float* __restrict__ maskv,
                                                    float* __restrict__ out) {
    __shared__ float r1[256], r2[256];
    int t = threadIdx.x;
    r1[t] = rloss[t];
    r2[t] = sumsq[t] * maskv[t];
    __syncthreads();
    for (int s2 = 128; s2 > 0; s2 >>= 1) {
        if (t < s2) { r1[t] += r1[t + s2]; r2[t] += r2[t + s2]; }
        __syncthreads();
    }
    if (t == 0) {
        float rec_loss = r1[0];
        float info = r2[0] / (float)BATCH;
        out[0] = rec_loss + 0.025f * info;
        out[1 + (size_t)BATCH * N_ENT] = rec_loss;
    }
}

// ---------------------------------------------------------------- launch
extern "C" void kernel_launch(void* const* d_in, const int* in_sizes, int n_in,
                              void* d_out, int out_size, void* d_ws, size_t ws_size,
                              hipStream_t stream) {
    (void)in_sizes; (void)n_in; (void)out_size;
    const int*   concept_mask  = (const int*)d_in[0];
    const int*   seed_pad      = (const int*)d_in[1];
    const int*   seed_lens     = (const int*)d_in[2];
    const int*   db_eidx       = (const int*)d_in[3];
    const int*   db_etype      = (const int*)d_in[4];
    const int*   con_eidx      = (const int*)d_in[5];
    const float* db_vec        = (const float*)d_in[6];
    const int*   labels        = (const int*)d_in[7];
    const float* rec           = (const float*)d_in[8];
    const float* concept_emb   = (const float*)d_in[9];
    const float* basis         = (const float*)d_in[10];
    const float* comp          = (const float*)d_in[11];
    const float* rgcn_root     = (const float*)d_in[12];
    const float* rgcn_bias     = (const float*)d_in[13];
    const float* gcn_w         = (const float*)d_in[14];
    const float* gcn_b         = (const float*)d_in[15];
    const float* attn_a        = (const float*)d_in[16];
    const float* attn_b        = (const float*)d_in[17];
    const float* attn_a_db     = (const float*)d_in[18];
    const float* attn_b_db     = (const float*)d_in[19];
    const float* user_norm_w   = (const float*)d_in[20];
    const float* user_norm_b   = (const float*)d_in[21];
    const float* gate_norm_w   = (const float*)d_in[22];
    const float* gate_norm_b   = (const float*)d_in[23];
    const float* info_con_w    = (const float*)d_in[24];
    const float* info_con_b    = (const float*)d_in[25];
    const float* info_out_db_b = (const float*)d_in[26];
    const float* output_en_b   = (const float*)d_in[27];

    float* ws = (float*)d_ws;
    size_t off = 0;
    auto alloc = [&](size_t n) { float* p = ws + off; off += (n + 255) & ~(size_t)255; return p; };
    float* dbf   = alloc((size_t)N_ENT * DIM);
    float* xw    = alloc((size_t)N_CON * DIM);
    float* conf  = alloc((size_t)N_CON * DIM);
    float* dinv  = alloc(N_CON);
    float* dbu   = alloc(BATCH * DIM);
    float* conu  = alloc(BATCH * DIM);
    float* maskv = alloc(BATCH);
    float* uemb  = alloc(BATCH * DIM);
    float* cone  = alloc(BATCH * DIM);
    float* ssq   = alloc(BATCH);
    float* rls   = alloc(BATCH);
    int* cnt_e    = (int*)alloc(N_ENT);
    int* rowptr_e = (int*)alloc(N_ENT + 1);
    int* cursor_e = (int*)alloc(N_ENT);
    int* elist_e  = (int*)alloc(EDB);
    int* cnt_c    = (int*)alloc(N_CON);
    int* rowptr_c = (int*)alloc(N_CON + 1);
    int* cursor_c = (int*)alloc(N_CON);
    int* elist_c  = (int*)alloc(ECON);
    size_t w_elems = (size_t)NREL * N_ENT * DIM;
    bool use_w = (off + w_elems) * sizeof(float) <= ws_size;
    float* w = ws + off;

    float* out    = (float*)d_out;
    float* escore = out + 1;

    hipMemsetAsync(cnt_e, 0, N_ENT * sizeof(int), stream);
    hipMemsetAsync(cnt_c, 0, N_CON * sizeof(int), stream);
    hipMemsetAsync(ssq,   0, BATCH * sizeof(float), stream);

    // CSR builds
    hist_kernel<<<(EDB + 255) / 256, 256, 0, stream>>>(db_eidx + EDB, EDB, cnt_e);
    hist_kernel<<<(ECON + 255) / 256, 256, 0, stream>>>(con_eidx + ECON, ECON, cnt_c);
    scan_kernel<<<1, 1024, 0, stream>>>(cnt_e, N_ENT, rowptr_e, cursor_e);
    scan_kernel<<<1, 1024, 0, stream>>>(cnt_c, N_CON, rowptr_c, cursor_c);
    scatter_rgcn_kernel<<<(EDB + 255) / 256, 256, 0, stream>>>(db_eidx, db_etype, cursor_e, elist_e);
    scatter_gcn_kernel<<<(ECON + 255) / 256, 256, 0, stream>>>(con_eidx, cursor_c, elist_c);

    // RGCN
    if (use_w) {
        wcomp_kernel<<<(N_ENT * 32 + 255) / 256, 256, 0, stream>>>(basis, comp, w);
        rgcn_gather_w<<<(N_ENT + 3) / 4, 256, 0, stream>>>(rowptr_e, elist_e, w,
                                                           rgcn_root, rgcn_bias, dbf);
    } else {
        rgcn_gather_basis<<<(N_ENT + 3) / 4, 256, 0, stream>>>(rowptr_e, elist_e, basis, comp,
                                                               rgcn_root, rgcn_bias, dbf);
    }

    // GCN
    gcn_xw_kernel<<<(N_CON + 15) / 16, 128, 0, stream>>>(concept_emb, gcn_w, xw);
    dinv_kernel<<<(N_CON + 255) / 256, 256, 0, stream>>>(cnt_c, dinv);
    gcn_gather<<<(N_CON + 3) / 4, 256, 0, stream>>>(rowptr_c, elist_c, dinv, xw, gcn_b, conf);

    // attention + fusion + scoring + losses
    attn_kernel<<<BATCH, 128, 0, stream>>>(dbf, seed_pad, seed_lens, attn_a_db, attn_b_db,
                                           dbu, maskv, SSEED, 0);
    attn_kernel<<<BATCH, 128, 0, stream>>>(conf, concept_mask, nullptr, attn_a, attn_b,
                                           conu, nullptr, LCON, 1);
    fusion_kernel<<<BATCH, 128, 0, stream>>>(conu, dbu, user_norm_w, user_norm_b,
                                             gate_norm_w, gate_norm_b, info_con_w, info_con_b,
                                             uemb, cone);
    dim3 sg((N_ENT + 63) / 64, BATCH / 32);
    score_kernel<<<sg, 256, 0, stream>>>(dbf, uemb, cone, output_en_b, info_out_db_b, db_vec,
                                         escore, ssq);
    ce_kernel<<<BATCH, 256, 0, stream>>>(escore, labels, rec, rls);
    final_kernel<<<1, 256, 0, stream>>>(rls, ssq, maskv, out);
}

// Round 4
// 652.434 us; speedup vs baseline: 2.3412x; 1.3981x over previous
//
#include <hip/hip_runtime.h>

#define N_ENT  30000
#define N_CON  29309
#define DIM    128
#define NBASIS 8
#define NREL   12
#define BATCH  256
#define LCON   50
#define SSEED  32
#define EDB    300000
#define ECON   200000
#define NTILE  938   // ceil(N_ENT/32)

typedef __attribute__((ext_vector_type(8)))  short bfrag8;   // 8 bf16 (4 VGPRs)
typedef __attribute__((ext_vector_type(16))) float facc16;   // 32x32 accumulator

__device__ __forceinline__ unsigned short f2bf(float f) {
    unsigned int u = __float_as_uint(f);
    u += 0x7FFFu + ((u >> 16) & 1u);
    return (unsigned short)(u >> 16);
}
__device__ __forceinline__ float bf2f(unsigned int h) {
    return __uint_as_float(h << 16);
}

// ---------------------------------------------------------------- CSR build
__global__ void hist_both_kernel(const int* __restrict__ db_dst, const int* __restrict__ con_dst,
                                 int* __restrict__ cnt_e, int* __restrict__ cnt_c) {
    int e = blockIdx.x * blockDim.x + threadIdx.x;
    if (e < EDB) atomicAdd(cnt_e + db_dst[e], 1);
    else if (e < EDB + ECON) atomicAdd(cnt_c + con_dst[e - EDB], 1);
}

__device__ void scan_block(const int* __restrict__ cnt, int n,
                           int* __restrict__ rowptr, int* __restrict__ cursor) {
    __shared__ int part[1024];
    int t = threadIdx.x;
    int per = (n + 1023) / 1024;
    int s0 = t * per;
    int sum = 0;
    for (int i = 0; i < per; ++i) {
        int idx = s0 + i;
        if (idx < n) sum += cnt[idx];
    }
    part[t] = sum;
    __syncthreads();
    for (int off = 1; off < 1024; off <<= 1) {
        int v = (t >= off) ? part[t - off] : 0;
        __syncthreads();
        part[t] += v;
        __syncthreads();
    }
    int run = part[t] - sum;
    for (int i = 0; i < per; ++i) {
        int idx = s0 + i;
        if (idx < n) {
            rowptr[idx] = run;
            cursor[idx] = run;
            run += cnt[idx];
        }
    }
    if (t == 1023) rowptr[n] = part[1023];
}

__global__ __launch_bounds__(1024) void scan2_kernel(const int* __restrict__ cnt_e,
                                                     const int* __restrict__ cnt_c,
                                                     int* __restrict__ rowptr_e, int* __restrict__ cursor_e,
                                                     int* __restrict__ rowptr_c, int* __restrict__ cursor_c,
                                                     float* __restrict__ dinv) {
    if (blockIdx.x == 0) {
        scan_block(cnt_e, N_ENT, rowptr_e, cursor_e);
    } else {
        scan_block(cnt_c, N_CON, rowptr_c, cursor_c);
        for (int i = threadIdx.x; i < N_CON; i += 1024)
            dinv[i] = rsqrtf((float)(cnt_c[i] + 1));
    }
}

__global__ void scatter_both_kernel(const int* __restrict__ db_eidx, const int* __restrict__ db_etype,
                                    const int* __restrict__ con_eidx,
                                    int* __restrict__ cursor_e, int* __restrict__ elist_e,
                                    int* __restrict__ cursor_c, int* __restrict__ elist_c) {
    int e = blockIdx.x * blockDim.x + threadIdx.x;
    if (e < EDB) {
        int dst = db_eidx[EDB + e];
        int pos = atomicAdd(cursor_e + dst, 1);
        elist_e[pos] = db_eidx[e] | (db_etype[e] << 18);
    } else if (e < EDB + ECON) {
        int ee = e - EDB;
        int dst = con_eidx[ECON + ee];
        int pos = atomicAdd(cursor_c + dst, 1);
        elist_c[pos] = con_eidx[ee];
    }
}

// ---------------------------------------------------------------- RGCN
// w_h[r,n,:] = bf16( sum_b comp[r,b] * basis[b,n,:] )
__global__ __launch_bounds__(256) void wcomp_h_kernel(const float* __restrict__ basis,
                                                      const float* __restrict__ comp,
                                                      unsigned short* __restrict__ w_h) {
    __shared__ float sc[NREL * NBASIS];
    int t = threadIdx.x;
    if (t < NREL * NBASIS) sc[t] = comp[t];
    __syncthreads();
    int i = blockIdx.x * blockDim.x + t;
    if (i >= N_ENT * 32) return;
    int n = i >> 5, d4 = i & 31;
    float4 bv[NBASIS];
#pragma unroll
    for (int b = 0; b < NBASIS; ++b)
        bv[b] = ((const float4*)(basis + ((size_t)b * N_ENT + n) * DIM))[d4];
#pragma unroll
    for (int r = 0; r < NREL; ++r) {
        float4 acc = make_float4(0.f, 0.f, 0.f, 0.f);
#pragma unroll
        for (int b = 0; b < NBASIS; ++b) {
            float c = sc[r * NBASIS + b];
            acc.x += c * bv[b].x; acc.y += c * bv[b].y;
            acc.z += c * bv[b].z; acc.w += c * bv[b].w;
        }
        unsigned int p0 = (unsigned int)f2bf(acc.x) | ((unsigned int)f2bf(acc.y) << 16);
        unsigned int p1 = (unsigned int)f2bf(acc.z) | ((unsigned int)f2bf(acc.w) << 16);
        *(uint2*)(w_h + ((size_t)r * N_ENT + n) * DIM + d4 * 4) = make_uint2(p0, p1);
    }
}

// one wave per dst entity; fused mean + root + bias; writes dbf fp32 + dbf_h bf16
__global__ __launch_bounds__(256) void rgcn_gather_wh(const int* __restrict__ rowptr,
                                                      const int* __restrict__ elist,
                                                      const unsigned short* __restrict__ w_h,
                                                      const float* __restrict__ root,
                                                      const float* __restrict__ bias,
                                                      float* __restrict__ dbf,
                                                      unsigned short* __restrict__ dbf_h) {
    int wid  = blockIdx.x * 4 + (threadIdx.x >> 6);
    int lane = threadIdx.x & 63;
    if (wid >= N_ENT) return;
    int beg = rowptr[wid], end = rowptr[wid + 1];
    float a0 = 0.f, a1 = 0.f;
    int p = beg;
    for (; p + 1 < end; p += 2) {
        int v0 = elist[p], v1 = elist[p + 1];
        unsigned int k0 = *(const unsigned int*)(w_h + ((size_t)(v0 >> 18) * N_ENT + (v0 & 0x3FFFF)) * DIM + lane * 2);
        unsigned int k1 = *(const unsigned int*)(w_h + ((size_t)(v1 >> 18) * N_ENT + (v1 & 0x3FFFF)) * DIM + lane * 2);
        a0 += bf2f(k0 & 0xFFFF) + bf2f(k1 & 0xFFFF);
        a1 += bf2f(k0 >> 16)    + bf2f(k1 >> 16);
    }
    if (p < end) {
        int v = elist[p];
        unsigned int k = *(const unsigned int*)(w_h + ((size_t)(v >> 18) * N_ENT + (v & 0x3FFFF)) * DIM + lane * 2);
        a0 += bf2f(k & 0xFFFF);
        a1 += bf2f(k >> 16);
    }
    float inv = 1.f / fmaxf((float)(end - beg), 1.f);
    size_t base = (size_t)wid * DIM + lane * 2;
    float f0 = a0 * inv + root[base]     + bias[lane * 2];
    float f1 = a1 * inv + root[base + 1] + bias[lane * 2 + 1];
    *(float2*)(dbf + base) = make_float2(f0, f1);
    *(unsigned int*)(dbf_h + base) = (unsigned int)f2bf(f0) | ((unsigned int)f2bf(f1) << 16);
}

// fallback when ws too small for w_h: gather straight from basis (fp32)
__global__ __launch_bounds__(256) void rgcn_gather_basis(const int* __restrict__ rowptr,
                                                         const int* __restrict__ elist,
                                                         const float* __restrict__ basis,
                                                         const float* __restrict__ comp,
                                                         const float* __restrict__ root,
                                                         const float* __restrict__ bias,
                                                         float* __restrict__ dbf,
                                                         unsigned short* __restrict__ dbf_h) {
    int wid  = blockIdx.x * 4 + (threadIdx.x >> 6);
    int lane = threadIdx.x & 63;
    if (wid >= N_ENT) return;
    int beg = rowptr[wid], end = rowptr[wid + 1];
    float a0 = 0.f, a1 = 0.f;
    for (int p = beg; p < end; ++p) {
        int v = elist[p];
        int src = v & 0x3FFFF, ty = v >> 18;
        const float* c = comp + ty * NBASIS;
#pragma unroll
        for (int b = 0; b < NBASIS; ++b) {
            const float* bp = basis + ((size_t)b * N_ENT + src) * DIM;
            a0 += c[b] * bp[lane * 2];
            a1 += c[b] * bp[lane * 2 + 1];
        }
    }
    float inv = 1.f / fmaxf((float)(end - beg), 1.f);
    size_t base = (size_t)wid * DIM + lane * 2;
    float f0 = a0 * inv + root[base]     + bias[lane * 2];
    float f1 = a1 * inv + root[base + 1] + bias[lane * 2 + 1];
    *(float2*)(dbf + base) = make_float2(f0, f1);
    *(unsigned int*)(dbf_h + base) = (unsigned int)f2bf(f0) | ((unsigned int)f2bf(f1) << 16);
}

// ---------------------------------------------------------------- conversions (emb->bf16, W->Wt bf16)
#define NE4 ((N_CON * DIM) / 4)    // 937888, exact
__global__ void conv_kernel(const float* __restrict__ emb, const float* __restrict__ W,
                            unsigned short* __restrict__ emb_h, unsigned short* __restrict__ Wt_h) {
    int i = blockIdx.x * blockDim.x + threadIdx.x;
    if (i < NE4) {
        float4 v = ((const float4*)emb)[i];
        unsigned int p0 = (unsigned int)f2bf(v.x) | ((unsigned int)f2bf(v.y) << 16);
        unsigned int p1 = (unsigned int)f2bf(v.z) | ((unsigned int)f2bf(v.w) << 16);
        *(uint2*)(emb_h + (size_t)i * 4) = make_uint2(p0, p1);
    } else {
        int j = i - NE4;
        if (j < (DIM * DIM) / 4) {
            int o = j * 4;
            int n = o >> 7, k0 = o & 127;
            unsigned int p0 = (unsigned int)f2bf(W[(k0 + 0) * DIM + n]) |
                              ((unsigned int)f2bf(W[(k0 + 1) * DIM + n]) << 16);
            unsigned int p1 = (unsigned int)f2bf(W[(k0 + 2) * DIM + n]) |
                              ((unsigned int)f2bf(W[(k0 + 3) * DIM + n]) << 16);
            *(uint2*)(Wt_h + n * DIM + k0) = make_uint2(p0, p1);
        }
    }
}

// ---------------------------------------------------------------- GCN xw via MFMA: xw_h = bf16(emb @ W)
__global__ __launch_bounds__(256) void gcn_xw_mfma(const unsigned short* __restrict__ emb_h,
                                                   const unsigned short* __restrict__ Wt_h,
                                                   unsigned short* __restrict__ xw_h) {
    int wave = threadIdx.x >> 6, lane = threadIdx.x & 63;
    int m0 = blockIdx.x * 32;
    int n0 = wave * 32;
    int am = lane & 31, ak = (lane >> 5) * 8;
    int mrow = m0 + am;
    bool mv = mrow < N_CON;
    const unsigned short* Ar = emb_h + (size_t)mrow * DIM + ak;
    const unsigned short* Br = Wt_h + (size_t)(n0 + am) * DIM + ak;
    facc16 acc;
#pragma unroll
    for (int r = 0; r < 16; ++r) acc[r] = 0.f;
#pragma unroll
    for (int s = 0; s < 8; ++s) {
        bfrag8 a;
#pragma unroll
        for (int j = 0; j < 8; ++j) a[j] = 0;
        if (mv) a = *(const bfrag8*)(Ar + s * 16);
        bfrag8 b = *(const bfrag8*)(Br + s * 16);
        acc = __builtin_amdgcn_mfma_f32_32x32x16_bf16(a, b, acc, 0, 0, 0);
    }
    int col = lane & 31;
    int g4 = (lane >> 5) * 4;
#pragma unroll
    for (int r = 0; r < 16; ++r) {
        int m = m0 + (r & 3) + ((r >> 2) << 3) + g4;
        if (m < N_CON) xw_h[(size_t)m * DIM + n0 + col] = f2bf(acc[r]);
    }
}

// one wave per concept node; conf = dv*(sum dinv[src]*xw[src]) + dv^2*xw[self] + bias (fp32 out)
__global__ __launch_bounds__(256) void gcn_gather(const int* __restrict__ rowptr,
                                                  const int* __restrict__ elist,
                                                  const float* __restrict__ dinv,
                                                  const unsigned short* __restrict__ xw_h,
                                                  const float* __restrict__ gcn_b,
                                                  float* __restrict__ conf) {
    int wid  = blockIdx.x * 4 + (threadIdx.x >> 6);
    int lane = threadIdx.x & 63;
    if (wid >= N_CON) return;
    int beg = rowptr[wid], end = rowptr[wid + 1];
    float a0 = 0.f, a1 = 0.f;
    int p = beg;
    for (; p + 1 < end; p += 2) {
        int s0 = elist[p], s1 = elist[p + 1];
        float n0 = dinv[s0], n1 = dinv[s1];
        unsigned int k0 = *(const unsigned int*)(xw_h + (size_t)s0 * DIM + lane * 2);
        unsigned int k1 = *(const unsigned int*)(xw_h + (size_t)s1 * DIM + lane * 2);
        a0 += n0 * bf2f(k0 & 0xFFFF) + n1 * bf2f(k1 & 0xFFFF);
        a1 += n0 * bf2f(k0 >> 16)    + n1 * bf2f(k1 >> 16);
    }
    if (p < end) {
        int s = elist[p];
        float nm = dinv[s];
        unsigned int k = *(const unsigned int*)(xw_h + (size_t)s * DIM + lane * 2);
        a0 += nm * bf2f(k & 0xFFFF);
        a1 += nm * bf2f(k >> 16);
    }
    float dv = dinv[wid];
    unsigned int ks = *(const unsigned int*)(xw_h + (size_t)wid * DIM + lane * 2);
    size_t base = (size_t)wid * DIM + lane * 2;
    float f0 = dv * a0 + dv * dv * bf2f(ks & 0xFFFF) + gcn_b[lane * 2];
    float f1 = dv * a1 + dv * dv * bf2f(ks >> 16)    + gcn_b[lane * 2 + 1];
    *(float2*)(conf + base) = make_float2(f0, f1);
}

// ---------------------------------------------------------------- masked attention (256 thr)
__global__ __launch_bounds__(256) void attn_kernel(const float* __restrict__ feats,
                                                   const int* __restrict__ idx,
                                                   const int* __restrict__ lens,
                                                   const float* __restrict__ A,
                                                   const float* __restrict__ vvec,
                                                   float* __restrict__ out_user,
                                                   float* __restrict__ out_mask,
                                                   int S, int mode) {
    __shared__ float h[LCON * DIM];
    __shared__ float sc[LCON];
    int b = blockIdx.x, t = threadIdx.x;
    const int* row = idx + b * S;
    for (int i = t; i < S * DIM; i += 256) {
        int s = i >> 7;
        h[i] = feats[(size_t)row[s] * DIM + (i & 127)];
    }
    if (t < S) sc[t] = 0.f;
    __syncthreads();
    for (int sd = t; sd < S * DIM; sd += 256) {
        int s = sd >> 7, d = sd & 127;
        float acc = 0.f;
        for (int k = 0; k < DIM; ++k) acc += h[(s << 7) + k] * A[(k << 7) + d];
        atomicAdd(&sc[s], tanhf(acc) * vvec[d]);
    }
    __syncthreads();
    int len = (mode == 0) ? lens[b] : 0;
    if (t == 0) {
        float m = -1e30f;
        for (int s = 0; s < S; ++s) {
            bool valid = (mode == 0) ? (s < len) : (row[s] != 0);
            float e = valid ? sc[s] : -1e30f;
            sc[s] = e;
            m = fmaxf(m, e);
        }
        float sum = 0.f;
        for (int s = 0; s < S; ++s) { float p = __expf(sc[s] - m); sum += p; sc[s] = p; }
        float inv = 1.f / sum;
        for (int s = 0; s < S; ++s) sc[s] *= inv;
    }
    __syncthreads();
    if (t < DIM) {
        float acc = 0.f;
        for (int s = 0; s < S; ++s) acc += sc[s] * h[(s << 7) + t];
        if (mode == 0 && len == 0) acc = 0.f;
        out_user[(size_t)b * DIM + t] = acc;
    }
    if (mode == 0 && t == 0) out_mask[b] = (len > 0) ? 1.f : 0.f;
}

// ---------------------------------------------------------------- gated fusion + info projection (bf16 out)
__global__ __launch_bounds__(128) void fusion_kernel(const float* __restrict__ con_user,
                                                     const float* __restrict__ db_user,
                                                     const float* __restrict__ Wu, const float* __restrict__ bu,
                                                     const float* __restrict__ gw, const float* __restrict__ gb,
                                                     const float* __restrict__ Wi, const float* __restrict__ bi,
                                                     unsigned short* __restrict__ uemb_h,
                                                     unsigned short* __restrict__ cone_h) {
    __shared__ float cu[DIM], du[DIM], red[DIM];
    int b = blockIdx.x, t = threadIdx.x;
    cu[t] = con_user[b * DIM + t];
    du[t] = db_user[b * DIM + t];
    __syncthreads();
    float u = bu[t];
    const float* wr = Wu + t * 2 * DIM;
    for (int k = 0; k < DIM; ++k) u += cu[k] * wr[k];
    for (int k = 0; k < DIM; ++k) u += du[k] * wr[DIM + k];
    red[t] = u * gw[t];
    __syncthreads();
    for (int s2 = 64; s2 > 0; s2 >>= 1) {
        if (t < s2) red[t] += red[t + s2];
        __syncthreads();
    }
    float gate = 1.f / (1.f + __expf(-(red[0] + gb[0])));
    uemb_h[b * DIM + t] = f2bf(gate * du[t] + (1.f - gate) * cu[t]);
    float ce = bi[t];
    const float* wi = Wi + t * DIM;
    for (int k = 0; k < DIM; ++k) ce += cu[k] * wi[k];
    cone_h[b * DIM + t] = f2bf(ce);
}

// ---------------------------------------------------------------- fused scoring GEMMs (MFMA) + CE/ssq partials
__global__ __launch_bounds__(256) void score_mfma(const unsigned short* __restrict__ dbf_h,
                                                  const unsigned short* __restrict__ uemb_h,
                                                  const unsigned short* __restrict__ cone_h,
                                                  const float* __restrict__ en_b,
                                                  const float* __restrict__ info_b,
                                                  const float* __restrict__ db_vec,
                                                  float* __restrict__ escore,
                                                  float* __restrict__ partM,
                                                  float* __restrict__ partS,
                                                  float* __restrict__ partQ) {
    int wave = threadIdx.x >> 6, lane = threadIdx.x & 63;
    int nt = blockIdx.x * 4 + wave;
    if (nt >= NTILE) return;
    int b0 = blockIdx.y * 32;
    int n0 = nt * 32;
    int am = lane & 31, ak = (lane >> 5) * 8;
    int nb = n0 + am;
    bool bvalid = nb < N_ENT;
    const unsigned short* Au = uemb_h + (size_t)(b0 + am) * DIM + ak;
    const unsigned short* Ac = cone_h + (size_t)(b0 + am) * DIM + ak;
    const unsigned short* Bp = dbf_h + (size_t)nb * DIM + ak;
    facc16 accE, accD;
#pragma unroll
    for (int r = 0; r < 16; ++r) { accE[r] = 0.f; accD[r] = 0.f; }
#pragma unroll
    for (int s = 0; s < 8; ++s) {
        bfrag8 au = *(const bfrag8*)(Au + s * 16);
        bfrag8 ac = *(const bfrag8*)(Ac + s * 16);
        bfrag8 bb;
#pragma unroll
        for (int j = 0; j < 8; ++j) bb[j] = 0;
        if (bvalid) bb = *(const bfrag8*)(Bp + s * 16);
        accE = __builtin_amdgcn_mfma_f32_32x32x16_bf16(au, bb, accE, 0, 0, 0);
        accD = __builtin_amdgcn_mfma_f32_32x32x16_bf16(ac, bb, accD, 0, 0, 0);
    }
    int col = lane & 31;
    int n = n0 + col;
    bool nv = n < N_ENT;
    float enb = nv ? en_b[n] : 0.f;
    float inb = nv ? info_b[n] : 0.f;
    int g4 = (lane >> 5) * 4;
#pragma unroll
    for (int r = 0; r < 16; ++r) {
        int b = b0 + (r & 3) + ((r >> 2) << 3) + g4;
        float e = accE[r] + enb;
        if (nv) escore[(size_t)b * N_ENT + n] = e;
        float ev = nv ? e : -1e30f;
        float mx = ev;
#pragma unroll
        for (int off = 16; off >= 1; off >>= 1) mx = fmaxf(mx, __shfl_xor(mx, off, 64));
        float ex = nv ? __expf(e - mx) : 0.f;
        float sm = ex;
#pragma unroll
        for (int off = 16; off >= 1; off >>= 1) sm += __shfl_xor(sm, off, 64);
        float d = nv ? (accD[r] + inb - db_vec[(size_t)b * N_ENT + n]) : 0.f;
        float q = d * d;
#pragma unroll
        for (int off = 16; off >= 1; off >>= 1) q += __shfl_xor(q, off, 64);
        if (col == 0) {
            partM[(size_t)b * NTILE + nt] = mx;
            partS[(size_t)b * NTILE + nt] = sm;
            partQ[(size_t)b * NTILE + nt] = q;
        }
    }
}

// ---------------------------------------------------------------- CE finalize from partials
__global__ __launch_bounds__(256) void ce_final(const float* __restrict__ partM,
                                                const float* __restrict__ partS,
                                                const float* __restrict__ partQ,
                                                const float* __restrict__ escore,
                                                const int* __restrict__ labels,
                                                const float* __restrict__ rec,
                                                float* __restrict__ rloss,
                                                float* __restrict__ ssqv) {
    __shared__ float red[256], red2[256];
    int b = blockIdx.x, t = threadIdx.x;
    const float* pm = partM + (size_t)b * NTILE;
    const float* ps = partS + (size_t)b * NTILE;
    const float* pq = partQ + (size_t)b * NTILE;
    float mx = -1e30f;
    for (int i = t; i < NTILE; i += 256) mx = fmaxf(mx, pm[i]);
    red[t] = mx;
    __syncthreads();
    for (int s2 = 128; s2 > 0; s2 >>= 1) {
        if (t < s2) red[t] = fmaxf(red[t], red[t + s2]);
        __syncthreads();
    }
    float M = red[0];
    __syncthreads();
    float s = 0.f, q = 0.f;
    for (int i = t; i < NTILE; i += 256) {
        s += ps[i] * __expf(pm[i] - M);
        q += pq[i];
    }
    red[t] = s; red2[t] = q;
    __syncthreads();
    for (int s2 = 128; s2 > 0; s2 >>= 1) {
        if (t < s2) { red[t] += red[t + s2]; red2[t] += red2[t + s2]; }
        __syncthreads();
    }
    if (t == 0) {
        float lse = M + logf(red[0]);
        float ce  = -(escore[(size_t)b * N_ENT + labels[b]] - lse);
        rloss[b]  = ce * rec[b];
        ssqv[b]   = red2[0];
    }
}

__global__ __launch_bounds__(256) void final_kernel(const float* __restrict__ rloss,
                                                    const float* __restrict__ sumsq,
                                                    const float* __restrict__ maskv,
                                                    float* __restrict__ out) {
    __shared__ float r1[256], r2[256];
    int t = threadIdx.x;
    r1[t] = rloss[t];
    r2[t] = sumsq[t] * maskv[t];
    __syncthreads();
    for (int s2 = 128; s2 > 0; s2 >>= 1) {
        if (t < s2) { r1[t] += r1[t + s2]; r2[t] += r2[t + s2]; }
        __syncthreads();
    }
    if (t == 0) {
        float rec_loss = r1[0];
        float info = r2[0] / (float)BATCH;
        out[0] = rec_loss + 0.025f * info;
        out[1 + (size_t)BATCH * N_ENT] = rec_loss;
    }
}

// ---------------------------------------------------------------- launch
extern "C" void kernel_launch(void* const* d_in, const int* in_sizes, int n_in,
                              void* d_out, int out_size, void* d_ws, size_t ws_size,
                              hipStream_t stream) {
    (void)in_sizes; (void)n_in; (void)out_size;
    const int*   concept_mask  = (const int*)d_in[0];
    const int*   seed_pad      = (const int*)d_in[1];
    const int*   seed_lens     = (const int*)d_in[2];
    const int*   db_eidx       = (const int*)d_in[3];
    const int*   db_etype      = (const int*)d_in[4];
    const int*   con_eidx      = (const int*)d_in[5];
    const float* db_vec        = (const float*)d_in[6];
    const int*   labels        = (const int*)d_in[7];
    const float* rec           = (const float*)d_in[8];
    const float* concept_emb   = (const float*)d_in[9];
    const float* basis         = (const float*)d_in[10];
    const float* comp          = (const float*)d_in[11];
    const float* rgcn_root     = (const float*)d_in[12];
    const float* rgcn_bias     = (const float*)d_in[13];
    const float* gcn_w         = (const float*)d_in[14];
    const float* gcn_b         = (const float*)d_in[15];
    const float* attn_a        = (const float*)d_in[16];
    const float* attn_b        = (const float*)d_in[17];
    const float* attn_a_db     = (const float*)d_in[18];
    const float* attn_b_db     = (const float*)d_in[19];
    const float* user_norm_w   = (const float*)d_in[20];
    const float* user_norm_b   = (const float*)d_in[21];
    const float* gate_norm_w   = (const float*)d_in[22];
    const float* gate_norm_b   = (const float*)d_in[23];
    const float* info_con_w    = (const float*)d_in[24];
    const float* info_con_b    = (const float*)d_in[25];
    const float* info_out_db_b = (const float*)d_in[26];
    const float* output_en_b   = (const float*)d_in[27];

    float* ws = (float*)d_ws;
    size_t off = 0;
    auto alloc = [&](size_t n) { float* p = ws + off; off += (n + 255) & ~(size_t)255; return p; };
    float* dbf    = alloc((size_t)N_ENT * DIM);
    float* conf   = alloc((size_t)N_CON * DIM);
    float* dinv   = alloc(N_CON);
    float* dbu    = alloc(BATCH * DIM);
    float* conu   = alloc(BATCH * DIM);
    float* maskv  = alloc(BATCH);
    float* rls    = alloc(BATCH);
    float* ssqv   = alloc(BATCH);
    float* partM  = alloc((size_t)BATCH * NTILE);
    float* partS  = alloc((size_t)BATCH * NTILE);
    float* partQ  = alloc((size_t)BATCH * NTILE);
    int* cnt_e    = (int*)alloc(N_ENT + N_CON);      // cnt_e and cnt_c contiguous for one memset
    int* cnt_c    = cnt_e + N_ENT;
    int* rowptr_e = (int*)alloc(N_ENT + 1);
    int* cursor_e = (int*)alloc(N_ENT);
    int* elist_e  = (int*)alloc(EDB);
    int* rowptr_c = (int*)alloc(N_CON + 1);
    int* cursor_c = (int*)alloc(N_CON);
    int* elist_c  = (int*)alloc(ECON);
    unsigned short* dbf_h  = (unsigned short*)alloc((size_t)N_ENT * DIM / 2);
    unsigned short* xw_h   = (unsigned short*)alloc((size_t)N_CON * DIM / 2 + 128);
    unsigned short* emb_h  = (unsigned short*)alloc((size_t)N_CON * DIM / 2 + 128);
    unsigned short* Wt_h   = (unsigned short*)alloc(DIM * DIM / 2);
    unsigned short* uemb_h = (unsigned short*)alloc(BATCH * DIM / 2);
    unsigned short* cone_h = (unsigned short*)alloc(BATCH * DIM / 2);
    size_t w_elems = ((size_t)NREL * N_ENT * DIM) / 2;   // bf16 as float-elems
    bool use_w = (off + w_elems) * sizeof(float) <= ws_size;
    unsigned short* w_h = (unsigned short*)(ws + off);

    float* out    = (float*)d_out;
    float* escore = out + 1;

    (void)hipMemsetAsync(cnt_e, 0, (N_ENT + N_CON) * sizeof(int), stream);

    // CSR builds (both graphs in shared dispatches)
    int gEC = (EDB + ECON + 255) / 256;
    hist_both_kernel<<<gEC, 256, 0, stream>>>(db_eidx + EDB, con_eidx + ECON, cnt_e, cnt_c);
    scan2_kernel<<<2, 1024, 0, stream>>>(cnt_e, cnt_c, rowptr_e, cursor_e, rowptr_c, cursor_c, dinv);
    scatter_both_kernel<<<gEC, 256, 0, stream>>>(db_eidx, db_etype, con_eidx,
                                                 cursor_e, elist_e, cursor_c, elist_c);

    // conversions
    conv_kernel<<<(NE4 + DIM * DIM / 4 + 255) / 256, 256, 0, stream>>>(concept_emb, gcn_w, emb_h, Wt_h);

    // RGCN
    if (use_w) {
        wcomp_h_kernel<<<(N_ENT * 32 + 255) / 256, 256, 0, stream>>>(basis, comp, w_h);
        rgcn_gather_wh<<<(N_ENT + 3) / 4, 256, 0, stream>>>(rowptr_e, elist_e, w_h,
                                                            rgcn_root, rgcn_bias, dbf, dbf_h);
    } else {
        rgcn_gather_basis<<<(N_ENT + 3) / 4, 256, 0, stream>>>(rowptr_e, elist_e, basis, comp,
                                                               rgcn_root, rgcn_bias, dbf, dbf_h);
    }

    // GCN
    gcn_xw_mfma<<<(N_CON + 31) / 32, 256, 0, stream>>>(emb_h, Wt_h, xw_h);
    gcn_gather<<<(N_CON + 3) / 4, 256, 0, stream>>>(rowptr_c, elist_c, dinv, xw_h, gcn_b, conf);

    // attention + fusion
    attn_kernel<<<BATCH, 256, 0, stream>>>(dbf, seed_pad, seed_lens, attn_a_db, attn_b_db,
                                           dbu, maskv, SSEED, 0);
    attn_kernel<<<BATCH, 256, 0, stream>>>(conf, concept_mask, nullptr, attn_a, attn_b,
                                           conu, nullptr, LCON, 1);
    fusion_kernel<<<BATCH, 128, 0, stream>>>(conu, dbu, user_norm_w, user_norm_b,
                                             gate_norm_w, gate_norm_b, info_con_w, info_con_b,
                                             uemb_h, cone_h);

    // scoring + losses
    dim3 sg((NTILE + 3) / 4, BATCH / 32);
    score_mfma<<<sg, 256, 0, stream>>>(dbf_h, uemb_h, cone_h, output_en_b, info_out_db_b, db_vec,
                                       escore, partM, partS, partQ);
    ce_final<<<BATCH, 256, 0, stream>>>(partM, partS, partQ, escore, labels, rec, rls, ssqv);
    final_kernel<<<1, 256, 0, stream>>>(rls, ssqv, maskv, out);
}

// Round 5
// 589.960 us; speedup vs baseline: 2.5892x; 1.1059x over previous
//
#include <hip/hip_runtime.h>

#define N_ENT  30000
#define N_CON  29309
#define DIM    128
#define NBASIS 8
#define NREL   12
#define BATCH  256
#define LCON   50
#define SSEED  32
#define EDB    300000
#define ECON   200000
#define NTILE  938   // ceil(N_ENT/32)

#define NE4      ((N_CON * DIM) / 4)          // 937888 (exact)
#define NB_HIST  ((EDB + ECON + 255) / 256)   // 1954
#define NB_CONV  ((NE4 + (DIM*DIM/4) + 255) / 256)
#define NB_WCOMP ((N_ENT * 32) / 256)         // 3750
#define NB_GXW   ((N_CON + 31) / 32)          // 916
#define NB_RG    ((N_ENT + 3) / 4)            // 7500
#define NB_GG    ((N_CON + 3) / 4)            // 7328

typedef __attribute__((ext_vector_type(8)))  short bfrag8;
typedef __attribute__((ext_vector_type(16))) float facc16;

__device__ __forceinline__ unsigned short f2bf(float f) {
    unsigned int u = __float_as_uint(f);
    u += 0x7FFFu + ((u >> 16) & 1u);
    return (unsigned short)(u >> 16);
}
__device__ __forceinline__ float bf2f(unsigned int h) {
    return __uint_as_float(h << 16);
}

// ============================ dispatch 1: hist (with ordinals) + bf16 conversions
__global__ __launch_bounds__(256) void prep_kernel(const int* __restrict__ db_dst,
                                                   const int* __restrict__ con_dst,
                                                   const float* __restrict__ emb,
                                                   const float* __restrict__ W,
                                                   int* __restrict__ cnt_e, int* __restrict__ cnt_c,
                                                   int* __restrict__ ord_db, int* __restrict__ ord_con,
                                                   unsigned short* __restrict__ emb_h,
                                                   unsigned short* __restrict__ Wt_h) {
    int t = threadIdx.x, bb = blockIdx.x;
    if (bb < NB_HIST) {
        int e = bb * 256 + t;
        if (e < EDB) {
            ord_db[e] = atomicAdd(cnt_e + db_dst[e], 1);
        } else if (e < EDB + ECON) {
            int ee = e - EDB;
            ord_con[ee] = atomicAdd(cnt_c + con_dst[ee], 1);
        }
    } else {
        int i = (bb - NB_HIST) * 256 + t;
        if (i < NE4) {
            float4 v = ((const float4*)emb)[i];
            unsigned int p0 = (unsigned int)f2bf(v.x) | ((unsigned int)f2bf(v.y) << 16);
            unsigned int p1 = (unsigned int)f2bf(v.z) | ((unsigned int)f2bf(v.w) << 16);
            *(uint2*)(emb_h + (size_t)i * 4) = make_uint2(p0, p1);
        } else {
            int j = i - NE4;
            if (j < (DIM * DIM) / 4) {
                int o = j * 4;
                int n = o >> 7, k0 = o & 127;
                unsigned int p0 = (unsigned int)f2bf(W[(k0 + 0) * DIM + n]) |
                                  ((unsigned int)f2bf(W[(k0 + 1) * DIM + n]) << 16);
                unsigned int p1 = (unsigned int)f2bf(W[(k0 + 2) * DIM + n]) |
                                  ((unsigned int)f2bf(W[(k0 + 3) * DIM + n]) << 16);
                *(uint2*)(Wt_h + n * DIM + k0) = make_uint2(p0, p1);
            }
        }
    }
}

// ============================ dispatch 2: two exclusive scans (+dinv)
__device__ void scan_block(const int* __restrict__ cnt, int n, int* __restrict__ rowptr) {
    __shared__ int part[1024];
    int t = threadIdx.x;
    int per = (n + 1023) / 1024;
    int s0 = t * per;
    int sum = 0;
    for (int i = 0; i < per; ++i) {
        int idx = s0 + i;
        if (idx < n) sum += cnt[idx];
    }
    part[t] = sum;
    __syncthreads();
    for (int off = 1; off < 1024; off <<= 1) {
        int v = (t >= off) ? part[t - off] : 0;
        __syncthreads();
        part[t] += v;
        __syncthreads();
    }
    int run = part[t] - sum;
    for (int i = 0; i < per; ++i) {
        int idx = s0 + i;
        if (idx < n) {
            rowptr[idx] = run;
            run += cnt[idx];
        }
    }
    if (t == 1023) rowptr[n] = part[1023];
}

__global__ __launch_bounds__(1024) void scan2_kernel(const int* __restrict__ cnt_e,
                                                     const int* __restrict__ cnt_c,
                                                     int* __restrict__ rowptr_e,
                                                     int* __restrict__ rowptr_c,
                                                     float* __restrict__ dinv) {
    if (blockIdx.x == 0) {
        scan_block(cnt_e, N_ENT, rowptr_e);
    } else {
        scan_block(cnt_c, N_CON, rowptr_c);
        for (int i = threadIdx.x; i < N_CON; i += 1024)
            dinv[i] = rsqrtf((float)(cnt_c[i] + 1));
    }
}

// ============================ dispatch 3: scatter + wcomp + gcn_xw MFMA (block-range fused)
__global__ __launch_bounds__(256) void mid_kernel(const int* __restrict__ db_eidx,
                                                  const int* __restrict__ db_etype,
                                                  const int* __restrict__ con_eidx,
                                                  const int* __restrict__ ord_db,
                                                  const int* __restrict__ ord_con,
                                                  const int* __restrict__ rowptr_e,
                                                  const int* __restrict__ rowptr_c,
                                                  int* __restrict__ elist_e,
                                                  int* __restrict__ elist_c,
                                                  const float* __restrict__ basis,
                                                  const float* __restrict__ comp,
                                                  unsigned short* __restrict__ w_h,
                                                  const unsigned short* __restrict__ emb_h,
                                                  const unsigned short* __restrict__ Wt_h,
                                                  unsigned short* __restrict__ xw_h,
                                                  int use_w) {
    __shared__ float sc[NREL * NBASIS];
    int t = threadIdx.x, bb = blockIdx.x;
    if (bb < NB_HIST) {
        // ---- scatter (pure writes, ordinals precomputed)
        int e = bb * 256 + t;
        if (e < EDB) {
            int dst = db_eidx[EDB + e];
            elist_e[rowptr_e[dst] + ord_db[e]] = db_eidx[e] | (db_etype[e] << 18);
        } else if (e < EDB + ECON) {
            int ee = e - EDB;
            int dst = con_eidx[ECON + ee];
            elist_c[rowptr_c[dst] + ord_con[ee]] = con_eidx[ee];
        }
        return;
    }
    if (bb < NB_HIST + NB_WCOMP) {
        // ---- w_h[r,n,:] = bf16(sum_b comp[r,b]*basis[b,n,:])
        if (!use_w) return;
        if (t < NREL * NBASIS) sc[t] = comp[t];
        __syncthreads();
        int i = (bb - NB_HIST) * 256 + t;
        int n = i >> 5, d4 = i & 31;
        float4 bv[NBASIS];
#pragma unroll
        for (int b = 0; b < NBASIS; ++b)
            bv[b] = ((const float4*)(basis + ((size_t)b * N_ENT + n) * DIM))[d4];
#pragma unroll
        for (int r = 0; r < NREL; ++r) {
            float4 acc = make_float4(0.f, 0.f, 0.f, 0.f);
#pragma unroll
            for (int b = 0; b < NBASIS; ++b) {
                float c = sc[r * NBASIS + b];
                acc.x += c * bv[b].x; acc.y += c * bv[b].y;
                acc.z += c * bv[b].z; acc.w += c * bv[b].w;
            }
            unsigned int p0 = (unsigned int)f2bf(acc.x) | ((unsigned int)f2bf(acc.y) << 16);
            unsigned int p1 = (unsigned int)f2bf(acc.z) | ((unsigned int)f2bf(acc.w) << 16);
            *(uint2*)(w_h + ((size_t)r * N_ENT + n) * DIM + d4 * 4) = make_uint2(p0, p1);
        }
        return;
    }
    // ---- xw_h = bf16(emb @ W) via MFMA
    {
        int gb = bb - NB_HIST - NB_WCOMP;
        int wave = t >> 6, lane = t & 63;
        int m0 = gb * 32;
        int n0 = wave * 32;
        int am = lane & 31, ak = (lane >> 5) * 8;
        int mrow = m0 + am;
        bool mv = mrow < N_CON;
        const unsigned short* Ar = emb_h + (size_t)mrow * DIM + ak;
        const unsigned short* Br = Wt_h + (size_t)(n0 + am) * DIM + ak;
        facc16 acc;
#pragma unroll
        for (int r = 0; r < 16; ++r) acc[r] = 0.f;
#pragma unroll
        for (int s = 0; s < 8; ++s) {
            bfrag8 a;
#pragma unroll
            for (int j = 0; j < 8; ++j) a[j] = 0;
            if (mv) a = *(const bfrag8*)(Ar + s * 16);
            bfrag8 b = *(const bfrag8*)(Br + s * 16);
            acc = __builtin_amdgcn_mfma_f32_32x32x16_bf16(a, b, acc, 0, 0, 0);
        }
        int col = lane & 31;
        int g4 = (lane >> 5) * 4;
#pragma unroll
        for (int r = 0; r < 16; ++r) {
            int m = m0 + (r & 3) + ((r >> 2) << 3) + g4;
            if (m < N_CON) xw_h[(size_t)m * DIM + n0 + col] = f2bf(acc[r]);
        }
    }
}

// ============================ dispatch 4: both graph gathers (block-range fused)
__global__ __launch_bounds__(256) void gathers_kernel(const int* __restrict__ rowptr_e,
                                                      const int* __restrict__ elist_e,
                                                      const unsigned short* __restrict__ w_h,
                                                      const float* __restrict__ root,
                                                      const float* __restrict__ bias,
                                                      unsigned short* __restrict__ dbf_h,
                                                      const int* __restrict__ rowptr_c,
                                                      const int* __restrict__ elist_c,
                                                      const float* __restrict__ dinv,
                                                      const unsigned short* __restrict__ xw_h,
                                                      const float* __restrict__ gcn_b,
                                                      unsigned short* __restrict__ conf_h) {
    int bb = blockIdx.x;
    int lane = threadIdx.x & 63;
    if (bb < NB_RG) {
        int wid = bb * 4 + (threadIdx.x >> 6);
        if (wid >= N_ENT) return;
        int beg = rowptr_e[wid], end = rowptr_e[wid + 1];
        float a0 = 0.f, a1 = 0.f;
        int p = beg;
        for (; p + 1 < end; p += 2) {
            int v0 = elist_e[p], v1 = elist_e[p + 1];
            unsigned int k0 = *(const unsigned int*)(w_h + ((size_t)(v0 >> 18) * N_ENT + (v0 & 0x3FFFF)) * DIM + lane * 2);
            unsigned int k1 = *(const unsigned int*)(w_h + ((size_t)(v1 >> 18) * N_ENT + (v1 & 0x3FFFF)) * DIM + lane * 2);
            a0 += bf2f(k0 & 0xFFFF) + bf2f(k1 & 0xFFFF);
            a1 += bf2f(k0 >> 16)    + bf2f(k1 >> 16);
        }
        if (p < end) {
            int v = elist_e[p];
            unsigned int k = *(const unsigned int*)(w_h + ((size_t)(v >> 18) * N_ENT + (v & 0x3FFFF)) * DIM + lane * 2);
            a0 += bf2f(k & 0xFFFF);
            a1 += bf2f(k >> 16);
        }
        float inv = 1.f / fmaxf((float)(end - beg), 1.f);
        size_t base = (size_t)wid * DIM + lane * 2;
        float f0 = a0 * inv + root[base]     + bias[lane * 2];
        float f1 = a1 * inv + root[base + 1] + bias[lane * 2 + 1];
        *(unsigned int*)(dbf_h + base) = (unsigned int)f2bf(f0) | ((unsigned int)f2bf(f1) << 16);
    } else {
        int wid = (bb - NB_RG) * 4 + (threadIdx.x >> 6);
        if (wid >= N_CON) return;
        int beg = rowptr_c[wid], end = rowptr_c[wid + 1];
        float a0 = 0.f, a1 = 0.f;
        int p = beg;
        for (; p + 1 < end; p += 2) {
            int s0 = elist_c[p], s1 = elist_c[p + 1];
            float n0 = dinv[s0], n1 = dinv[s1];
            unsigned int k0 = *(const unsigned int*)(xw_h + (size_t)s0 * DIM + lane * 2);
            unsigned int k1 = *(const unsigned int*)(xw_h + (size_t)s1 * DIM + lane * 2);
            a0 += n0 * bf2f(k0 & 0xFFFF) + n1 * bf2f(k1 & 0xFFFF);
            a1 += n0 * bf2f(k0 >> 16)    + n1 * bf2f(k1 >> 16);
        }
        if (p < end) {
            int s = elist_c[p];
            float nm = dinv[s];
            unsigned int k = *(const unsigned int*)(xw_h + (size_t)s * DIM + lane * 2);
            a0 += nm * bf2f(k & 0xFFFF);
            a1 += nm * bf2f(k >> 16);
        }
        float dv = dinv[wid];
        unsigned int ks = *(const unsigned int*)(xw_h + (size_t)wid * DIM + lane * 2);
        size_t base = (size_t)wid * DIM + lane * 2;
        float f0 = dv * a0 + dv * dv * bf2f(ks & 0xFFFF) + gcn_b[lane * 2];
        float f1 = dv * a1 + dv * dv * bf2f(ks >> 16)    + gcn_b[lane * 2 + 1];
        *(unsigned int*)(conf_h + base) = (unsigned int)f2bf(f0) | ((unsigned int)f2bf(f1) << 16);
    }
}

// fallback when ws too small for w_h: RGCN gather straight from fp32 basis
__global__ __launch_bounds__(256) void rgcn_gather_basis(const int* __restrict__ rowptr,
                                                         const int* __restrict__ elist,
                                                         const float* __restrict__ basis,
                                                         const float* __restrict__ comp,
                                                         const float* __restrict__ root,
                                                         const float* __restrict__ bias,
                                                         unsigned short* __restrict__ dbf_h) {
    int wid  = blockIdx.x * 4 + (threadIdx.x >> 6);
    int lane = threadIdx.x & 63;
    if (wid >= N_ENT) return;
    int beg = rowptr[wid], end = rowptr[wid + 1];
    float a0 = 0.f, a1 = 0.f;
    for (int p = beg; p < end; ++p) {
        int v = elist[p];
        int src = v & 0x3FFFF, ty = v >> 18;
        const float* c = comp + ty * NBASIS;
#pragma unroll
        for (int b = 0; b < NBASIS; ++b) {
            const float* bp = basis + ((size_t)b * N_ENT + src) * DIM;
            a0 += c[b] * bp[lane * 2];
            a1 += c[b] * bp[lane * 2 + 1];
        }
    }
    float inv = 1.f / fmaxf((float)(end - beg), 1.f);
    size_t base = (size_t)wid * DIM + lane * 2;
    float f0 = a0 * inv + root[base]     + bias[lane * 2];
    float f1 = a1 * inv + root[base + 1] + bias[lane * 2 + 1];
    *(unsigned int*)(dbf_h + base) = (unsigned int)f2bf(f0) | ((unsigned int)f2bf(f1) << 16);
}

// ============================ dispatch 5: both attentions + gated fusion per sample
__device__ void attn_phase(const unsigned short* __restrict__ feats_h,
                           const int* __restrict__ row,
                           const float* __restrict__ A,
                           const float* __restrict__ vvec,
                           float* __restrict__ h, float* __restrict__ sc,
                           float* __restrict__ outv, int S, int len, int mode) {
    int t = threadIdx.x;
    for (int i = t; i < S * (DIM / 2); i += 256) {
        int s = i >> 6, d2 = (i & 63) * 2;
        unsigned int k = *(const unsigned int*)(feats_h + (size_t)row[s] * DIM + d2);
        h[(s << 7) + d2]     = bf2f(k & 0xFFFF);
        h[(s << 7) + d2 + 1] = bf2f(k >> 16);
    }
    if (t < S) sc[t] = 0.f;
    __syncthreads();
    for (int sd = t; sd < S * DIM; sd += 256) {
        int s = sd >> 7, d = sd & 127;
        float acc = 0.f;
        for (int k = 0; k < DIM; ++k) acc += h[(s << 7) + k] * A[(k << 7) + d];
        atomicAdd(&sc[s], tanhf(acc) * vvec[d]);
    }
    __syncthreads();
    if (t == 0) {
        float m = -1e30f;
        for (int s = 0; s < S; ++s) {
            bool valid = (mode == 0) ? (s < len) : (row[s] != 0);
            float e = valid ? sc[s] : -1e30f;
            sc[s] = e;
            m = fmaxf(m, e);
        }
        float sum = 0.f;
        for (int s = 0; s < S; ++s) { float p = __expf(sc[s] - m); sum += p; sc[s] = p; }
        float inv = 1.f / sum;
        for (int s = 0; s < S; ++s) sc[s] *= inv;
    }
    __syncthreads();
    if (t < DIM) {
        float acc = 0.f;
        for (int s = 0; s < S; ++s) acc += sc[s] * h[(s << 7) + t];
        if (mode == 0 && len == 0) acc = 0.f;
        outv[t] = acc;
    }
    __syncthreads();
}

__global__ __launch_bounds__(256) void attn_fusion_kernel(const unsigned short* __restrict__ dbf_h,
                                                          const unsigned short* __restrict__ conf_h,
                                                          const int* __restrict__ seed_pad,
                                                          const int* __restrict__ seed_lens,
                                                          const int* __restrict__ concept_mask,
                                                          const float* __restrict__ A_db, const float* __restrict__ v_db,
                                                          const float* __restrict__ A_c,  const float* __restrict__ v_c,
                                                          const float* __restrict__ Wu, const float* __restrict__ bu,
                                                          const float* __restrict__ gw, const float* __restrict__ gb,
                                                          const float* __restrict__ Wi, const float* __restrict__ bi,
                                                          unsigned short* __restrict__ uemb_h,
                                                          unsigned short* __restrict__ cone_h,
                                                          float* __restrict__ maskv) {
    __shared__ float h[LCON * DIM];
    __shared__ float sc[LCON];
    __shared__ float du[DIM], cu[DIM], red[DIM];
    int b = blockIdx.x, t = threadIdx.x;
    int len = seed_lens[b];
    attn_phase(dbf_h, seed_pad + b * SSEED, A_db, v_db, h, sc, du, SSEED, len, 0);
    attn_phase(conf_h, concept_mask + b * LCON, A_c, v_c, h, sc, cu, LCON, 0, 1);
    // fusion
    if (t < DIM) {
        float u = bu[t];
        const float* wr = Wu + t * 2 * DIM;
        for (int k = 0; k < DIM; ++k) u += cu[k] * wr[k];
        for (int k = 0; k < DIM; ++k) u += du[k] * wr[DIM + k];
        red[t] = u * gw[t];
    }
    __syncthreads();
    for (int s2 = 64; s2 > 0; s2 >>= 1) {
        if (t < s2) red[t] += red[t + s2];
        __syncthreads();
    }
    if (t < DIM) {
        float gate = 1.f / (1.f + __expf(-(red[0] + gb[0])));
        uemb_h[b * DIM + t] = f2bf(gate * du[t] + (1.f - gate) * cu[t]);
        float ce = bi[t];
        const float* wi = Wi + t * DIM;
        for (int k = 0; k < DIM; ++k) ce += cu[k] * wi[k];
        cone_h[b * DIM + t] = f2bf(ce);
    }
    if (t == 0) maskv[b] = (len > 0) ? 1.f : 0.f;
}

// ============================ dispatch 6: fused scoring GEMMs (MFMA) + CE/ssq partials
__global__ __launch_bounds__(256) void score_mfma(const unsigned short* __restrict__ dbf_h,
                                                  const unsigned short* __restrict__ uemb_h,
                                                  const unsigned short* __restrict__ cone_h,
                                                  const float* __restrict__ en_b,
                                                  const float* __restrict__ info_b,
                                                  const float* __restrict__ db_vec,
                                                  float* __restrict__ escore,
                                                  float* __restrict__ partM,
                                                  float* __restrict__ partS,
                                                  float* __restrict__ partQ) {
    int wave = threadIdx.x >> 6, lane = threadIdx.x & 63;
    int nt = blockIdx.x * 4 + wave;
    if (nt >= NTILE) return;
    int b0 = blockIdx.y * 32;
    int n0 = nt * 32;
    int am = lane & 31, ak = (lane >> 5) * 8;
    int nb = n0 + am;
    bool bvalid = nb < N_ENT;
    const unsigned short* Au = uemb_h + (size_t)(b0 + am) * DIM + ak;
    const unsigned short* Ac = cone_h + (size_t)(b0 + am) * DIM + ak;
    const unsigned short* Bp = dbf_h + (size_t)nb * DIM + ak;
    facc16 accE, accD;
#pragma unroll
    for (int r = 0; r < 16; ++r) { accE[r] = 0.f; accD[r] = 0.f; }
#pragma unroll
    for (int s = 0; s < 8; ++s) {
        bfrag8 au = *(const bfrag8*)(Au + s * 16);
        bfrag8 ac = *(const bfrag8*)(Ac + s * 16);
        bfrag8 bb;
#pragma unroll
        for (int j = 0; j < 8; ++j) bb[j] = 0;
        if (bvalid) bb = *(const bfrag8*)(Bp + s * 16);
        accE = __builtin_amdgcn_mfma_f32_32x32x16_bf16(au, bb, accE, 0, 0, 0);
        accD = __builtin_amdgcn_mfma_f32_32x32x16_bf16(ac, bb, accD, 0, 0, 0);
    }
    int col = lane & 31;
    int n = n0 + col;
    bool nv = n < N_ENT;
    float enb = nv ? en_b[n] : 0.f;
    float inb = nv ? info_b[n] : 0.f;
    int g4 = (lane >> 5) * 4;
#pragma unroll
    for (int r = 0; r < 16; ++r) {
        int b = b0 + (r & 3) + ((r >> 2) << 3) + g4;
        float e = accE[r] + enb;
        if (nv) escore[(size_t)b * N_ENT + n] = e;
        float ev = nv ? e : -1e30f;
        float mx = ev;
#pragma unroll
        for (int off = 16; off >= 1; off >>= 1) mx = fmaxf(mx, __shfl_xor(mx, off, 64));
        float ex = nv ? __expf(e - mx) : 0.f;
        float sm = ex;
#pragma unroll
        for (int off = 16; off >= 1; off >>= 1) sm += __shfl_xor(sm, off, 64);
        float d = nv ? (accD[r] + inb - db_vec[(size_t)b * N_ENT + n]) : 0.f;
        float q = d * d;
#pragma unroll
        for (int off = 16; off >= 1; off >>= 1) q += __shfl_xor(q, off, 64);
        if (col == 0) {
            partM[(size_t)b * NTILE + nt] = mx;
            partS[(size_t)b * NTILE + nt] = sm;
            partQ[(size_t)b * NTILE + nt] = q;
        }
    }
}

// ============================ dispatch 7: CE finalize from partials
__global__ __launch_bounds__(256) void ce_final(const float* __restrict__ partM,
                                                const float* __restrict__ partS,
                                                const float* __restrict__ partQ,
                                                const float* __restrict__ escore,
                                                const int* __restrict__ labels,
                                                const float* __restrict__ rec,
                                                float* __restrict__ rloss,
                                                float* __restrict__ ssqv) {
    __shared__ float red[256], red2[256];
    int b = blockIdx.x, t = threadIdx.x;
    const float* pm = partM + (size_t)b * NTILE;
    const float* ps = partS + (size_t)b * NTILE;
    const float* pq = partQ + (size_t)b * NTILE;
    float mx = -1e30f;
    for (int i = t; i < NTILE; i += 256) mx = fmaxf(mx, pm[i]);
    red[t] = mx;
    __syncthreads();
    for (int s2 = 128; s2 > 0; s2 >>= 1) {
        if (t < s2) red[t] = fmaxf(red[t], red[t + s2]);
        __syncthreads();
    }
    float M = red[0];
    __syncthreads();
    float s = 0.f, q = 0.f;
    for (int i = t; i < NTILE; i += 256) {
        s += ps[i] * __expf(pm[i] - M);
        q += pq[i];
    }
    red[t] = s; red2[t] = q;
    __syncthreads();
    for (int s2 = 128; s2 > 0; s2 >>= 1) {
        if (t < s2) { red[t] += red[t + s2]; red2[t] += red2[t + s2]; }
        __syncthreads();
    }
    if (t == 0) {
        float lse = M + logf(red[0]);
        float ce  = -(escore[(size_t)b * N_ENT + labels[b]] - lse);
        rloss[b]  = ce * rec[b];
        ssqv[b]   = red2[0];
    }
}

// ============================ dispatch 8: final scalar reduction
__global__ __launch_bounds__(256) void final_kernel(const float* __restrict__ rloss,
                                                    const float* __restrict__ sumsq,
                                                    const float* __restrict__ maskv,
                                                    float* __restrict__ out) {
    __shared__ float r1[256], r2[256];
    int t = threadIdx.x;
    r1[t] = rloss[t];
    r2[t] = sumsq[t] * maskv[t];
    __syncthreads();
    for (int s2 = 128; s2 > 0; s2 >>= 1) {
        if (t < s2) { r1[t] += r1[t + s2]; r2[t] += r2[t + s2]; }
        __syncthreads();
    }
    if (t == 0) {
        float rec_loss = r1[0];
        float info = r2[0] / (float)BATCH;
        out[0] = rec_loss + 0.025f * info;
        out[1 + (size_t)BATCH * N_ENT] = rec_loss;
    }
}

// ============================ launch
extern "C" void kernel_launch(void* const* d_in, const int* in_sizes, int n_in,
                              void* d_out, int out_size, void* d_ws, size_t ws_size,
                              hipStream_t stream) {
    (void)in_sizes; (void)n_in; (void)out_size;
    const int*   concept_mask  = (const int*)d_in[0];
    const int*   seed_pad      = (const int*)d_in[1];
    const int*   seed_lens     = (const int*)d_in[2];
    const int*   db_eidx       = (const int*)d_in[3];
    const int*   db_etype      = (const int*)d_in[4];
    const int*   con_eidx      = (const int*)d_in[5];
    const float* db_vec        = (const float*)d_in[6];
    const int*   labels        = (const int*)d_in[7];
    const float* rec           = (const float*)d_in[8];
    const float* concept_emb   = (const float*)d_in[9];
    const float* basis         = (const float*)d_in[10];
    const float* comp          = (const float*)d_in[11];
    const float* rgcn_root     = (const float*)d_in[12];
    const float* rgcn_bias     = (const float*)d_in[13];
    const float* gcn_w         = (const float*)d_in[14];
    const float* gcn_b         = (const float*)d_in[15];
    const float* attn_a        = (const float*)d_in[16];
    const float* attn_b        = (const float*)d_in[17];
    const float* attn_a_db     = (const float*)d_in[18];
    const float* attn_b_db     = (const float*)d_in[19];
    const float* user_norm_w   = (const float*)d_in[20];
    const float* user_norm_b   = (const float*)d_in[21];
    const float* gate_norm_w   = (const float*)d_in[22];
    const float* gate_norm_b   = (const float*)d_in[23];
    const float* info_con_w    = (const float*)d_in[24];
    const float* info_con_b    = (const float*)d_in[25];
    const float* info_out_db_b = (const float*)d_in[26];
    const float* output_en_b   = (const float*)d_in[27];

    float* ws = (float*)d_ws;
    size_t off = 0;
    auto alloc = [&](size_t n) { float* p = ws + off; off += (n + 255) & ~(size_t)255; return p; };
    float* dinv   = alloc(N_CON);
    float* maskv  = alloc(BATCH);
    float* rls    = alloc(BATCH);
    float* ssqv   = alloc(BATCH);
    float* partM  = alloc((size_t)BATCH * NTILE);
    float* partS  = alloc((size_t)BATCH * NTILE);
    float* partQ  = alloc((size_t)BATCH * NTILE);
    int* cnt_e    = (int*)alloc(N_ENT + N_CON);     // contiguous for one memset
    int* cnt_c    = cnt_e + N_ENT;
    int* rowptr_e = (int*)alloc(N_ENT + 1);
    int* rowptr_c = (int*)alloc(N_CON + 1);
    int* ord_db   = (int*)alloc(EDB);
    int* ord_con  = (int*)alloc(ECON);
    int* elist_e  = (int*)alloc(EDB);
    int* elist_c  = (int*)alloc(ECON);
    unsigned short* dbf_h  = (unsigned short*)alloc((size_t)N_ENT * DIM / 2);
    unsigned short* conf_h = (unsigned short*)alloc((size_t)N_CON * DIM / 2 + 128);
    unsigned short* xw_h   = (unsigned short*)alloc((size_t)N_CON * DIM / 2 + 128);
    unsigned short* emb_h  = (unsigned short*)alloc((size_t)N_CON * DIM / 2 + 128);
    unsigned short* Wt_h   = (unsigned short*)alloc(DIM * DIM / 2);
    unsigned short* uemb_h = (unsigned short*)alloc(BATCH * DIM / 2);
    unsigned short* cone_h = (unsigned short*)alloc(BATCH * DIM / 2);
    size_t w_elems = ((size_t)NREL * N_ENT * DIM) / 2;   // bf16 in float-units
    int use_w = (off + w_elems) * sizeof(float) <= ws_size;
    unsigned short* w_h = (unsigned short*)(ws + off);

    float* out    = (float*)d_out;
    float* escore = out + 1;

    (void)hipMemsetAsync(cnt_e, 0, (N_ENT + N_CON) * sizeof(int), stream);

    prep_kernel<<<NB_HIST + NB_CONV, 256, 0, stream>>>(db_eidx + EDB, con_eidx + ECON,
                                                       concept_emb, gcn_w,
                                                       cnt_e, cnt_c, ord_db, ord_con, emb_h, Wt_h);
    scan2_kernel<<<2, 1024, 0, stream>>>(cnt_e, cnt_c, rowptr_e, rowptr_c, dinv);
    mid_kernel<<<NB_HIST + NB_WCOMP + NB_GXW, 256, 0, stream>>>(db_eidx, db_etype, con_eidx,
                                                                ord_db, ord_con, rowptr_e, rowptr_c,
                                                                elist_e, elist_c, basis, comp, w_h,
                                                                emb_h, Wt_h, xw_h, use_w);
    gathers_kernel<<<NB_RG + NB_GG, 256, 0, stream>>>(rowptr_e, elist_e, w_h, rgcn_root, rgcn_bias,
                                                      dbf_h, rowptr_c, elist_c, dinv, xw_h, gcn_b, conf_h);
    if (!use_w) {
        rgcn_gather_basis<<<NB_RG, 256, 0, stream>>>(rowptr_e, elist_e, basis, comp,
                                                     rgcn_root, rgcn_bias, dbf_h);
    }
    attn_fusion_kernel<<<BATCH, 256, 0, stream>>>(dbf_h, conf_h, seed_pad, seed_lens, concept_mask,
                                                  attn_a_db, attn_b_db, attn_a, attn_b,
                                                  user_norm_w, user_norm_b, gate_norm_w, gate_norm_b,
                                                  info_con_w, info_con_b, uemb_h, cone_h, maskv);
    dim3 sg((NTILE + 3) / 4, BATCH / 32);
    score_mfma<<<sg, 256, 0, stream>>>(dbf_h, uemb_h, cone_h, output_en_b, info_out_db_b, db_vec,
                                       escore, partM, partS, partQ);
    ce_final<<<BATCH, 256, 0, stream>>>(partM, partS, partQ, escore, labels, rec, rls, ssqv);
    final_kernel<<<1, 256, 0, stream>>>(rls, ssqv, maskv, out);
}